// Round 6
// baseline (1736.592 us; speedup 1.0000x reference)
//
#include <hip/hip_runtime.h>

#define N_NODES 100000
#define N_EDGES 3200000
#define N_GRAPHS 1000
#define NLAYER 4
#define NB 391           // coarse buckets: dst>>8, 391*256 = 100096 >= N_NODES
#define G1 782           // edge-pass blocks: 782*4096 >= N_EDGES
#define EPB 4096         // edges per block in edge passes

// round-to-nearest-even f32 -> bf16 (finite inputs)
static __device__ __forceinline__ unsigned f2bf(float f) {
  unsigned u = __float_as_uint(f);
  return (u + 0x7fffu + ((u >> 16) & 1u)) >> 16;
}

__device__ __forceinline__ void fma4(float4& a, float s, const float4& w) {
  a.x = fmaf(s, w.x, a.x);
  a.y = fmaf(s, w.y, a.y);
  a.z = fmaf(s, w.z, a.z);
  a.w = fmaf(s, w.w, a.w);
}

// ---------------------------------------------------------------------------
// h[v][c] = sum_k x[v][k]*emb_w[k][c] + emb_b[c]
__global__ __launch_bounds__(256) void embed_kernel(
    const float* __restrict__ x, const float* __restrict__ emb_w,
    const float* __restrict__ emb_b, float* __restrict__ h)
{
  int t = blockIdx.x * 256 + threadIdx.x;
  if (t >= N_NODES * 64) return;
  int c = t & 63, v = t >> 6;
  float4 xv = ((const float4*)x)[v];
  float acc = emb_b[c];
  acc = fmaf(xv.x, emb_w[0 * 64 + c], acc);
  acc = fmaf(xv.y, emb_w[1 * 64 + c], acc);
  acc = fmaf(xv.z, emb_w[2 * 64 + c], acc);
  acc = fmaf(xv.w, emb_w[3 * 64 + c], acc);
  h[t] = acc;
}

// ---------------------------------------------------------------------------
// A: per-block LDS histogram of coarse bucket (dst>>8). No device atomics.
__global__ __launch_bounds__(256) void bhist_kernel(
    const int* __restrict__ ei, int* __restrict__ bhist)
{
  __shared__ unsigned hist[NB];
  for (int i = threadIdx.x; i < NB; i += 256) hist[i] = 0;
  __syncthreads();
  int base = blockIdx.x * EPB;
#pragma unroll
  for (int i = 0; i < 16; ++i) {
    int e = base + i * 256 + threadIdx.x;
    if (e < N_EDGES) atomicAdd(&hist[((unsigned)ei[N_EDGES + e]) >> 8], 1u);
  }
  __syncthreads();
  for (int i = threadIdx.x; i < NB; i += 256)
    bhist[blockIdx.x * NB + i] = (int)hist[i];
}

// B1: per-bucket column exclusive scan over the G1 block rows (in place);
// column total -> tots[b]
__global__ __launch_bounds__(256) void colscan_kernel(
    int* __restrict__ bhist, int* __restrict__ tots)
{
  int b = blockIdx.x;  // bucket
  __shared__ int s[256];
  __shared__ int carry;
  if (threadIdx.x == 0) carry = 0;
  __syncthreads();
  for (int c0 = 0; c0 < G1; c0 += 256) {
    int g = c0 + threadIdx.x;
    int v = (g < G1) ? bhist[g * NB + b] : 0;
    s[threadIdx.x] = v;
    __syncthreads();
    for (int off = 1; off < 256; off <<= 1) {
      int y = (threadIdx.x >= off) ? s[threadIdx.x - off] : 0;
      __syncthreads();
      s[threadIdx.x] += y;
      __syncthreads();
    }
    if (g < G1) bhist[g * NB + b] = carry + s[threadIdx.x] - v;  // exclusive
    __syncthreads();
    if (threadIdx.x == 0) carry += s[255];
    __syncthreads();
  }
  if (threadIdx.x == 0) tots[b] = carry;
}

// B2: exclusive scan of bucket totals -> bucket base offsets bb[0..NB]
__global__ __launch_bounds__(512) void bucketscan_kernel(
    const int* __restrict__ tots, int* __restrict__ bb)
{
  __shared__ int s[512];
  int x = ((int)threadIdx.x < NB) ? tots[threadIdx.x] : 0;
  s[threadIdx.x] = x;
  __syncthreads();
  for (int off = 1; off < 512; off <<= 1) {
    int y = (threadIdx.x >= off) ? s[threadIdx.x - off] : 0;
    __syncthreads();
    s[threadIdx.x] += y;
    __syncthreads();
  }
  if ((int)threadIdx.x < NB) bb[threadIdx.x] = s[threadIdx.x] - x;
  if (threadIdx.x == 0) bb[NB] = N_EDGES;
}

// C: scatter edges into coarse buckets. LDS cursors only (no device atomics).
// record: x = src | ((dst&255)<<17)   (src < 2^17), y = ew bits (exact f32)
__global__ __launch_bounds__(256) void bscatter_kernel(
    const int* __restrict__ ei, const float* __restrict__ ea,
    const int* __restrict__ bhist, const int* __restrict__ bb,
    int2* __restrict__ tmp)
{
  __shared__ unsigned cur[NB];
  for (int i = threadIdx.x; i < NB; i += 256)
    cur[i] = (unsigned)(bb[i] + bhist[blockIdx.x * NB + i]);
  __syncthreads();
  int base = blockIdx.x * EPB;
#pragma unroll
  for (int i = 0; i < 16; ++i) {
    int e = base + i * 256 + threadIdx.x;
    if (e < N_EDGES) {
      int d = ei[N_EDGES + e];
      int srcv = ei[e];
      float w = ea[e];
      unsigned pos = atomicAdd(&cur[((unsigned)d) >> 8], 1u);
      tmp[pos] = make_int2(srcv | ((d & 255) << 17), __float_as_int(w));
    }
  }
}

// D: one block per bucket: 256-bin LDS counting sort within bucket ->
// final dst-sorted csr (coalesced window), plus row_off and degw for free.
__global__ __launch_bounds__(256) void bucket_sort_kernel(
    const int* __restrict__ bb, const int2* __restrict__ tmp,
    int2* __restrict__ csr, int* __restrict__ row_off, float* __restrict__ degw)
{
  int j = blockIdx.x;
  int b0 = bb[j], b1 = bb[j + 1];
  int nE = b1 - b0;
  __shared__ unsigned hist[256];
  __shared__ float dws[256];
  __shared__ int scanbuf[256];
  __shared__ unsigned cur[256];
  int t = threadIdx.x;
  hist[t] = 0;
  dws[t] = 0.f;
  __syncthreads();
  for (int i = t; i < nE; i += 256) {
    int2 r = tmp[b0 + i];
    int bin = ((unsigned)r.x) >> 17;
    atomicAdd(&hist[bin], 1u);
    atomicAdd(&dws[bin], __int_as_float(r.y));
  }
  __syncthreads();
  int v = (int)hist[t];
  scanbuf[t] = v;
  __syncthreads();
  for (int off = 1; off < 256; off <<= 1) {
    int y = (t >= off) ? scanbuf[t - off] : 0;
    __syncthreads();
    scanbuf[t] += y;
    __syncthreads();
  }
  int myexcl = scanbuf[t] - v;
  cur[t] = (unsigned)myexcl;
  int vnode = (j << 8) + t;
  if (vnode < N_NODES) {
    row_off[vnode] = b0 + myexcl;
    degw[vnode] = dws[t];
  }
  if (j == NB - 1 && t == 0) row_off[N_NODES] = N_EDGES;
  __syncthreads();
  for (int i = t; i < nE; i += 256) {
    int2 r = tmp[b0 + i];
    int bin = ((unsigned)r.x) >> 17;
    unsigned p = atomicAdd(&cur[bin], 1u);
    csr[b0 + (int)p] = make_int2(r.x & 0x1FFFF, r.y);
  }
}

// ---------------------------------------------------------------------------
// fused 3-matvec, 4 threads per node (16 channels each), no LDS, no sync:
//   a_out  = bf16(h@W1 + b1)
//   cc_out = b3 + h@W3 - deg_w * (h@W2)   (fp32)
__global__ __launch_bounds__(256) void matvec3_kernel(
    const float* __restrict__ h,
    const float* __restrict__ w1, const float* __restrict__ b1,
    const float* __restrict__ w2,
    const float* __restrict__ w3, const float* __restrict__ b3,
    const float* __restrict__ degw,
    uint2* __restrict__ a_out, float* __restrict__ cc_out)
{
  int t = blockIdx.x * 256 + threadIdx.x;
  int v = t >> 2;               // node
  int c0 = (t & 3) * 4;         // first channel-quad (channels 16*(t&3)..+15)
  if (v >= N_NODES) return;
  const float4* hp = (const float4*)(h + (size_t)v * 64);
  const float4* w1q = (const float4*)w1;
  const float4* w2q = (const float4*)w2;
  const float4* w3q = (const float4*)w3;
  float dw = degw[v];
  float4 acc[4];

  // ---- phase W2: acc = h@W2 ----
#pragma unroll
  for (int jj = 0; jj < 4; ++jj) acc[jj] = make_float4(0.f, 0.f, 0.f, 0.f);
#pragma unroll 4
  for (int k4 = 0; k4 < 16; ++k4) {
    float4 hk = hp[k4];
    const float4* wr = w2q + (k4 * 4) * 16 + c0;
#pragma unroll
    for (int jj = 0; jj < 4; ++jj) {
      fma4(acc[jj], hk.x, wr[jj]);
      fma4(acc[jj], hk.y, wr[16 + jj]);
      fma4(acc[jj], hk.z, wr[32 + jj]);
      fma4(acc[jj], hk.w, wr[48 + jj]);
    }
  }
#pragma unroll
  for (int jj = 0; jj < 4; ++jj) {
    acc[jj].x *= -dw; acc[jj].y *= -dw; acc[jj].z *= -dw; acc[jj].w *= -dw;
  }

  // ---- phase W3: acc += h@W3; += b3; store cc (fp32) ----
#pragma unroll 4
  for (int k4 = 0; k4 < 16; ++k4) {
    float4 hk = hp[k4];
    const float4* wr = w3q + (k4 * 4) * 16 + c0;
#pragma unroll
    for (int jj = 0; jj < 4; ++jj) {
      fma4(acc[jj], hk.x, wr[jj]);
      fma4(acc[jj], hk.y, wr[16 + jj]);
      fma4(acc[jj], hk.z, wr[32 + jj]);
      fma4(acc[jj], hk.w, wr[48 + jj]);
    }
  }
  {
    const float4* b3q = (const float4*)b3;
    float4* ccp = (float4*)(cc_out + (size_t)v * 64);
#pragma unroll
    for (int jj = 0; jj < 4; ++jj) {
      float4 bb3 = b3q[c0 + jj];
      float4 o = acc[jj];
      o.x += bb3.x; o.y += bb3.y; o.z += bb3.z; o.w += bb3.w;
      ccp[c0 + jj] = o;
    }
  }

  // ---- phase W1: acc = b1 + h@W1; store a (bf16) ----
  {
    const float4* b1q = (const float4*)b1;
#pragma unroll
    for (int jj = 0; jj < 4; ++jj) acc[jj] = b1q[c0 + jj];
  }
#pragma unroll 4
  for (int k4 = 0; k4 < 16; ++k4) {
    float4 hk = hp[k4];
    const float4* wr = w1q + (k4 * 4) * 16 + c0;
#pragma unroll
    for (int jj = 0; jj < 4; ++jj) {
      fma4(acc[jj], hk.x, wr[jj]);
      fma4(acc[jj], hk.y, wr[16 + jj]);
      fma4(acc[jj], hk.z, wr[32 + jj]);
      fma4(acc[jj], hk.w, wr[48 + jj]);
    }
  }
  {
    uint2* ap = a_out + (size_t)v * 16;
#pragma unroll
    for (int jj = 0; jj < 4; ++jj) {
      float4 o = acc[jj];
      uint2 p;
      p.x = f2bf(o.x) | (f2bf(o.y) << 16);
      p.y = f2bf(o.z) | (f2bf(o.w) << 16);
      ap[c0 + jj] = p;
    }
  }
}

// ---------------------------------------------------------------------------
// h_new[v] = relu(cc[v] + sum_{e in CSR(v)} ew_e * a[src_e])
// 4 nodes/wave, 16 lanes per node; a-rows bf16 (128 B).
__global__ __launch_bounds__(256) void agg_kernel(
    const uint2* __restrict__ a2, const float4* __restrict__ cc4,
    const int* __restrict__ row_off, const int2* __restrict__ csr,
    float4* __restrict__ h4)
{
  int wave = (blockIdx.x * 256 + threadIdx.x) >> 6;
  int lane = threadIdx.x & 63;
  int sg = lane >> 4;
  int li = lane & 15;
  int v = wave * 4 + sg;
  bool valid = v < N_NODES;
  int vc = valid ? v : N_NODES - 1;
  int base = row_off[vc];
  int ecnt = valid ? (row_off[vc + 1] - base) : 0;
  int emax = ecnt;
  emax = max(emax, __shfl_xor(emax, 16));
  emax = max(emax, __shfl_xor(emax, 32));

  float4 acc = valid ? cc4[(size_t)vc * 16 + li] : make_float4(0.f, 0.f, 0.f, 0.f);

  int full = emax & ~15;
  int c0 = 0;
  for (; c0 < full; c0 += 16) {
    int idx = c0 + li;
    int2 er = (idx < ecnt) ? csr[base + idx] : make_int2(0, 0);
#pragma unroll
    for (int j = 0; j < 16; ++j) {
      int sl = sg * 16 + j;
      int s = __shfl(er.x, sl);
      float w = __int_as_float(__shfl(er.y, sl));
      uint2 u = a2[(size_t)s * 16 + li];
      acc.x = fmaf(w, __uint_as_float(u.x << 16), acc.x);
      acc.y = fmaf(w, __uint_as_float(u.x & 0xffff0000u), acc.y);
      acc.z = fmaf(w, __uint_as_float(u.y << 16), acc.z);
      acc.w = fmaf(w, __uint_as_float(u.y & 0xffff0000u), acc.w);
    }
  }
  int rem = emax - full;
  if (rem > 0) {
    int idx = c0 + li;
    int2 er = (idx < ecnt) ? csr[base + idx] : make_int2(0, 0);
    for (int j = 0; j < rem; ++j) {
      int sl = sg * 16 + j;
      int s = __shfl(er.x, sl);
      float w = __int_as_float(__shfl(er.y, sl));
      uint2 u = a2[(size_t)s * 16 + li];
      acc.x = fmaf(w, __uint_as_float(u.x << 16), acc.x);
      acc.y = fmaf(w, __uint_as_float(u.x & 0xffff0000u), acc.y);
      acc.z = fmaf(w, __uint_as_float(u.y << 16), acc.z);
      acc.w = fmaf(w, __uint_as_float(u.y & 0xffff0000u), acc.w);
    }
  }
  if (valid) {
    acc.x = fmaxf(acc.x, 0.f);
    acc.y = fmaxf(acc.y, 0.f);
    acc.z = fmaxf(acc.z, 0.f);
    acc.w = fmaxf(acc.w, 0.f);
    h4[(size_t)v * 16 + li] = acc;
  }
}

// ---------------------------------------------------------------------------
// fused mean-pool (sorted batch, binary search) + lin1+relu + lin2, wave/graph
__global__ __launch_bounds__(256) void head_kernel(
    const float* __restrict__ h, const int* __restrict__ batch,
    const float* __restrict__ l1w, const float* __restrict__ l1b,
    const float* __restrict__ l2w, const float* __restrict__ l2b,
    float* __restrict__ out)
{
  int g = (blockIdx.x * 256 + threadIdx.x) >> 6;
  int lane = threadIdx.x & 63;
  if (g >= N_GRAPHS) return;
  int lo = 0, hi = N_NODES;
  while (lo < hi) { int mid = (lo + hi) >> 1; if (batch[mid] < g) lo = mid + 1; else hi = mid; }
  int start = lo;
  hi = N_NODES;
  while (lo < hi) { int mid = (lo + hi) >> 1; if (batch[mid] < g + 1) lo = mid + 1; else hi = mid; }
  int end = lo;

  float sum = 0.f;
  for (int v = start; v < end; ++v) sum += h[(size_t)v * 64 + lane];
  float cntf = (float)(end - start);
  float gx = sum / fmaxf(cntf, 1.f);

  float acc = l1b[lane];
  for (int k = 0; k < 64; ++k) {
    float gxk = __shfl(gx, k);
    acc = fmaf(gxk, l1w[k * 64 + lane], acc);
  }
  float t = fmaxf(acc, 0.f);
  float p0 = t * l2w[lane * 3 + 0];
  float p1 = t * l2w[lane * 3 + 1];
  float p2 = t * l2w[lane * 3 + 2];
  for (int off = 32; off > 0; off >>= 1) {
    p0 += __shfl_down(p0, off);
    p1 += __shfl_down(p1, off);
    p2 += __shfl_down(p2, off);
  }
  if (lane == 0) {
    out[g * 3 + 0] = p0 + l2b[0];
    out[g * 3 + 1] = p1 + l2b[1];
    out[g * 3 + 2] = p2 + l2b[2];
  }
}

// ---------------------------------------------------------------------------
extern "C" void kernel_launch(void* const* d_in, const int* in_sizes, int n_in,
                              void* d_out, int out_size, void* d_ws, size_t ws_size,
                              hipStream_t stream)
{
  (void)in_sizes; (void)n_in; (void)out_size; (void)ws_size;
  const float* x     = (const float*)d_in[0];
  const int*   ei    = (const int*)d_in[1];
  const float* ea    = (const float*)d_in[2];
  const int*   batch = (const int*)d_in[3];
  const float* emb_w = (const float*)d_in[4];
  const float* emb_b = (const float*)d_in[5];
  const float* cw1   = (const float*)d_in[6];
  const float* cb1   = (const float*)d_in[7];
  const float* cw2   = (const float*)d_in[8];
  const float* cw3   = (const float*)d_in[9];
  const float* cb3   = (const float*)d_in[10];
  const float* l1w   = (const float*)d_in[11];
  const float* l1b   = (const float*)d_in[12];
  const float* l2w   = (const float*)d_in[13];
  const float* l2b   = (const float*)d_in[14];
  float* out = (float*)d_out;

  char* wsb = (char*)d_ws;
  size_t off = 0;
  auto alloc = [&](size_t bytes) {
    char* p = wsb + off;
    off = (off + bytes + 255) & ~(size_t)255;
    return p;
  };
  float* h       = (float*)alloc(sizeof(float) * (size_t)N_NODES * 64);
  uint2* a_bf    = (uint2*)alloc(sizeof(uint2) * (size_t)N_NODES * 16);
  float* cc_buf  = (float*)alloc(sizeof(float) * (size_t)N_NODES * 64);
  int2*  csr     = (int2*)alloc(sizeof(int2) * (size_t)N_EDGES);
  int*   row_off = (int*)alloc(sizeof(int) * (N_NODES + 1));
  float* degw    = (float*)alloc(sizeof(float) * N_NODES);
  int*   bhist   = (int*)alloc(sizeof(int) * (size_t)G1 * NB);
  int*   tots    = (int*)alloc(sizeof(int) * NB);
  int*   bb      = (int*)alloc(sizeof(int) * (NB + 1));
  // tmp bucket records alias cc_buf: tmp is dead before matvec first writes cc.
  int2* tmp = (int2*)cc_buf;

  embed_kernel<<<(N_NODES * 64 + 255) / 256, 256, 0, stream>>>(x, emb_w, emb_b, h);
  bhist_kernel<<<G1, 256, 0, stream>>>(ei, bhist);
  colscan_kernel<<<NB, 256, 0, stream>>>(bhist, tots);
  bucketscan_kernel<<<1, 512, 0, stream>>>(tots, bb);
  bscatter_kernel<<<G1, 256, 0, stream>>>(ei, ea, bhist, bb, tmp);
  bucket_sort_kernel<<<NB, 256, 0, stream>>>(bb, tmp, csr, row_off, degw);

  int agg_blocks = (N_NODES + 15) / 16;
  int mv_blocks = (N_NODES * 4 + 255) / 256;  // 4 threads/node -> 1563 blocks
  for (int l = 0; l < NLAYER; ++l) {
    matvec3_kernel<<<mv_blocks, 256, 0, stream>>>(
        h, cw1 + l * 4096, cb1 + l * 64, cw2 + l * 4096, cw3 + l * 4096,
        cb3 + l * 64, degw, a_bf, cc_buf);
    agg_kernel<<<agg_blocks, 256, 0, stream>>>(
        a_bf, (const float4*)cc_buf, row_off, csr, (float4*)h);
  }

  head_kernel<<<(N_GRAPHS * 64 + 255) / 256, 256, 0, stream>>>(
      h, batch, l1w, l1b, l2w, l2b, out);
}

// Round 7
// 747.744 us; speedup vs baseline: 2.3224x; 2.3224x over previous
//
#include <hip/hip_runtime.h>

#define N_NODES 100000
#define N_EDGES 3200000
#define N_GRAPHS 1000
#define NLAYER 4
#define NB 391           // coarse buckets: dst>>8, 391*256 = 100096 >= N_NODES
#define G1 782           // edge-pass blocks: 782*4096 >= N_EDGES
#define EPB 4096         // edges per block in edge passes

// round-to-nearest-even f32 -> bf16 (finite inputs)
static __device__ __forceinline__ unsigned f2bf(float f) {
  unsigned u = __float_as_uint(f);
  return (u + 0x7fffu + ((u >> 16) & 1u)) >> 16;
}

__device__ __forceinline__ void fma4(float4& a, float s, const float4& w) {
  a.x = fmaf(s, w.x, a.x);
  a.y = fmaf(s, w.y, a.y);
  a.z = fmaf(s, w.z, a.z);
  a.w = fmaf(s, w.w, a.w);
}

// ---------------------------------------------------------------------------
// h[v][c] = sum_k x[v][k]*emb_w[k][c] + emb_b[c]
__global__ __launch_bounds__(256) void embed_kernel(
    const float* __restrict__ x, const float* __restrict__ emb_w,
    const float* __restrict__ emb_b, float* __restrict__ h)
{
  int t = blockIdx.x * 256 + threadIdx.x;
  if (t >= N_NODES * 64) return;
  int c = t & 63, v = t >> 6;
  float4 xv = ((const float4*)x)[v];
  float acc = emb_b[c];
  acc = fmaf(xv.x, emb_w[0 * 64 + c], acc);
  acc = fmaf(xv.y, emb_w[1 * 64 + c], acc);
  acc = fmaf(xv.z, emb_w[2 * 64 + c], acc);
  acc = fmaf(xv.w, emb_w[3 * 64 + c], acc);
  h[t] = acc;
}

// ---------------------------------------------------------------------------
// A: per-block LDS histogram of coarse bucket (dst>>8). No device atomics.
__global__ __launch_bounds__(256) void bhist_kernel(
    const int* __restrict__ ei, int* __restrict__ bhist)
{
  __shared__ unsigned hist[NB];
  for (int i = threadIdx.x; i < NB; i += 256) hist[i] = 0;
  __syncthreads();
  int base = blockIdx.x * EPB;
#pragma unroll
  for (int i = 0; i < 16; ++i) {
    int e = base + i * 256 + threadIdx.x;
    if (e < N_EDGES) atomicAdd(&hist[((unsigned)ei[N_EDGES + e]) >> 8], 1u);
  }
  __syncthreads();
  for (int i = threadIdx.x; i < NB; i += 256)
    bhist[blockIdx.x * NB + i] = (int)hist[i];
}

// B1: per-bucket column exclusive scan over the G1 block rows (in place);
// column total -> tots[b]
__global__ __launch_bounds__(256) void colscan_kernel(
    int* __restrict__ bhist, int* __restrict__ tots)
{
  int b = blockIdx.x;  // bucket
  __shared__ int s[256];
  __shared__ int carry;
  if (threadIdx.x == 0) carry = 0;
  __syncthreads();
  for (int c0 = 0; c0 < G1; c0 += 256) {
    int g = c0 + threadIdx.x;
    int v = (g < G1) ? bhist[g * NB + b] : 0;
    s[threadIdx.x] = v;
    __syncthreads();
    for (int off = 1; off < 256; off <<= 1) {
      int y = (threadIdx.x >= off) ? s[threadIdx.x - off] : 0;
      __syncthreads();
      s[threadIdx.x] += y;
      __syncthreads();
    }
    if (g < G1) bhist[g * NB + b] = carry + s[threadIdx.x] - v;  // exclusive
    __syncthreads();
    if (threadIdx.x == 0) carry += s[255];
    __syncthreads();
  }
  if (threadIdx.x == 0) tots[b] = carry;
}

// B2: exclusive scan of bucket totals -> bucket base offsets bb[0..NB]
__global__ __launch_bounds__(512) void bucketscan_kernel(
    const int* __restrict__ tots, int* __restrict__ bb)
{
  __shared__ int s[512];
  int x = ((int)threadIdx.x < NB) ? tots[threadIdx.x] : 0;
  s[threadIdx.x] = x;
  __syncthreads();
  for (int off = 1; off < 512; off <<= 1) {
    int y = (threadIdx.x >= off) ? s[threadIdx.x - off] : 0;
    __syncthreads();
    s[threadIdx.x] += y;
    __syncthreads();
  }
  if ((int)threadIdx.x < NB) bb[threadIdx.x] = s[threadIdx.x] - x;
  if (threadIdx.x == 0) bb[NB] = N_EDGES;
}

// C: scatter edges into coarse buckets. LDS cursors only (no device atomics).
// record: x = src | ((dst&255)<<17)   (src < 2^17), y = ew bits (exact f32)
__global__ __launch_bounds__(256) void bscatter_kernel(
    const int* __restrict__ ei, const float* __restrict__ ea,
    const int* __restrict__ bhist, const int* __restrict__ bb,
    int2* __restrict__ tmp)
{
  __shared__ unsigned cur[NB];
  for (int i = threadIdx.x; i < NB; i += 256)
    cur[i] = (unsigned)(bb[i] + bhist[blockIdx.x * NB + i]);
  __syncthreads();
  int base = blockIdx.x * EPB;
#pragma unroll
  for (int i = 0; i < 16; ++i) {
    int e = base + i * 256 + threadIdx.x;
    if (e < N_EDGES) {
      int d = ei[N_EDGES + e];
      int srcv = ei[e];
      float w = ea[e];
      unsigned pos = atomicAdd(&cur[((unsigned)d) >> 8], 1u);
      tmp[pos] = make_int2(srcv | ((d & 255) << 17), __float_as_int(w));
    }
  }
}

// D: one block per bucket: 256-bin LDS counting sort within bucket ->
// final dst-sorted csr (coalesced window), plus row_off and degw for free.
__global__ __launch_bounds__(256) void bucket_sort_kernel(
    const int* __restrict__ bb, const int2* __restrict__ tmp,
    int2* __restrict__ csr, int* __restrict__ row_off, float* __restrict__ degw)
{
  int j = blockIdx.x;
  int b0 = bb[j], b1 = bb[j + 1];
  int nE = b1 - b0;
  __shared__ unsigned hist[256];
  __shared__ float dws[256];
  __shared__ int scanbuf[256];
  __shared__ unsigned cur[256];
  int t = threadIdx.x;
  hist[t] = 0;
  dws[t] = 0.f;
  __syncthreads();
  for (int i = t; i < nE; i += 256) {
    int2 r = tmp[b0 + i];
    int bin = ((unsigned)r.x) >> 17;
    atomicAdd(&hist[bin], 1u);
    atomicAdd(&dws[bin], __int_as_float(r.y));
  }
  __syncthreads();
  int v = (int)hist[t];
  scanbuf[t] = v;
  __syncthreads();
  for (int off = 1; off < 256; off <<= 1) {
    int y = (t >= off) ? scanbuf[t - off] : 0;
    __syncthreads();
    scanbuf[t] += y;
    __syncthreads();
  }
  int myexcl = scanbuf[t] - v;
  cur[t] = (unsigned)myexcl;
  int vnode = (j << 8) + t;
  if (vnode < N_NODES) {
    row_off[vnode] = b0 + myexcl;
    degw[vnode] = dws[t];
  }
  if (j == NB - 1 && t == 0) row_off[N_NODES] = N_EDGES;
  __syncthreads();
  for (int i = t; i < nE; i += 256) {
    int2 r = tmp[b0 + i];
    int bin = ((unsigned)r.x) >> 17;
    unsigned p = atomicAdd(&cur[bin], 1u);
    csr[b0 + (int)p] = make_int2(r.x & 0x1FFFF, r.y);
  }
}

// ---------------------------------------------------------------------------
// fused 3-matvec: 4 threads/node, 16 channels each, 64 nodes/block.
// Weights LDS-broadcast; h-row in registers. Grid = 1563 blocks.
//   a_out  = bf16(h@W1 + b1)
//   cc_out = b3 + h@W3 - deg_w * (h@W2)   (fp32)
__global__ __launch_bounds__(256) void matvec3_kernel(
    const float* __restrict__ h,
    const float* __restrict__ w1, const float* __restrict__ b1,
    const float* __restrict__ w2,
    const float* __restrict__ w3, const float* __restrict__ b3,
    const float* __restrict__ degw,
    uint2* __restrict__ a_out, float* __restrict__ cc_out)
{
  // LDS: [0..1023]=W2, [1024..2047]=W3, [2048..3071]=W1 (float4 granules)
  __shared__ float4 ws[3 * 1024];
  int tid = threadIdx.x;
  {
    const float4* w1v = (const float4*)w1;
    const float4* w2v = (const float4*)w2;
    const float4* w3v = (const float4*)w3;
    for (int i = tid; i < 1024; i += 256) {
      ws[i] = w2v[i];
      ws[1024 + i] = w3v[i];
      ws[2048 + i] = w1v[i];
    }
  }
  __syncthreads();

  int v = blockIdx.x * 64 + (tid >> 2);
  int cg = tid & 3;  // channel group: channels cg*16 .. cg*16+15
  if (v >= N_NODES) return;  // no further barriers below

  const float4* hp = (const float4*)(h + (size_t)v * 64);
  float4 hr[16];
#pragma unroll
  for (int i = 0; i < 16; ++i) hr[i] = hp[i];
  float dw = degw[v];
  float4 acc[4];

  // weight float4 granule for (k, channel c): k*16 + c/4.
  // k = k4*4+kk -> granule = k4*64 + kk*16 + cg*4 + j
  auto phase = [&](int base) {
#pragma unroll
    for (int k4 = 0; k4 < 16; ++k4) {
      float4 hk = hr[k4];
      const float4* wr = &ws[base + k4 * 64 + cg * 4];
#pragma unroll
      for (int j = 0; j < 4; ++j) {
        fma4(acc[j], hk.x, wr[j]);
        fma4(acc[j], hk.y, wr[16 + j]);
        fma4(acc[j], hk.z, wr[32 + j]);
        fma4(acc[j], hk.w, wr[48 + j]);
      }
    }
  };

  // ---- cc: acc = h@W2; *= -dw; += h@W3; += b3; store fp32 ----
#pragma unroll
  for (int j = 0; j < 4; ++j) acc[j] = make_float4(0.f, 0.f, 0.f, 0.f);
  phase(0);
#pragma unroll
  for (int j = 0; j < 4; ++j) {
    acc[j].x *= -dw; acc[j].y *= -dw; acc[j].z *= -dw; acc[j].w *= -dw;
  }
  phase(1024);
  {
    const float4* b3q = (const float4*)b3;
    float4* ccp = (float4*)(cc_out + (size_t)v * 64);
#pragma unroll
    for (int j = 0; j < 4; ++j) {
      float4 bb3 = b3q[cg * 4 + j];
      float4 o = acc[j];
      o.x += bb3.x; o.y += bb3.y; o.z += bb3.z; o.w += bb3.w;
      ccp[cg * 4 + j] = o;
    }
  }

  // ---- a: acc = b1 + h@W1; store bf16 ----
  {
    const float4* b1q = (const float4*)b1;
#pragma unroll
    for (int j = 0; j < 4; ++j) acc[j] = b1q[cg * 4 + j];
  }
  phase(2048);
  {
    uint2* ap = a_out + (size_t)v * 16;
#pragma unroll
    for (int j = 0; j < 4; ++j) {
      float4 o = acc[j];
      uint2 p;
      p.x = f2bf(o.x) | (f2bf(o.y) << 16);
      p.y = f2bf(o.z) | (f2bf(o.w) << 16);
      ap[cg * 4 + j] = p;
    }
  }
}

// ---------------------------------------------------------------------------
// h_new[v] = relu(cc[v] + sum_{e in CSR(v)} ew_e * a[src_e])
// 4 nodes/wave, 16 lanes per node; a-rows bf16 (128 B).
__global__ __launch_bounds__(256) void agg_kernel(
    const uint2* __restrict__ a2, const float4* __restrict__ cc4,
    const int* __restrict__ row_off, const int2* __restrict__ csr,
    float4* __restrict__ h4)
{
  int wave = (blockIdx.x * 256 + threadIdx.x) >> 6;
  int lane = threadIdx.x & 63;
  int sg = lane >> 4;
  int li = lane & 15;
  int v = wave * 4 + sg;
  bool valid = v < N_NODES;
  int vc = valid ? v : N_NODES - 1;
  int base = row_off[vc];
  int ecnt = valid ? (row_off[vc + 1] - base) : 0;
  int emax = ecnt;
  emax = max(emax, __shfl_xor(emax, 16));
  emax = max(emax, __shfl_xor(emax, 32));

  float4 acc = valid ? cc4[(size_t)vc * 16 + li] : make_float4(0.f, 0.f, 0.f, 0.f);

  int full = emax & ~15;
  int c0 = 0;
  for (; c0 < full; c0 += 16) {
    int idx = c0 + li;
    int2 er = (idx < ecnt) ? csr[base + idx] : make_int2(0, 0);
#pragma unroll
    for (int j = 0; j < 16; ++j) {
      int sl = sg * 16 + j;
      int s = __shfl(er.x, sl);
      float w = __int_as_float(__shfl(er.y, sl));
      uint2 u = a2[(size_t)s * 16 + li];
      acc.x = fmaf(w, __uint_as_float(u.x << 16), acc.x);
      acc.y = fmaf(w, __uint_as_float(u.x & 0xffff0000u), acc.y);
      acc.z = fmaf(w, __uint_as_float(u.y << 16), acc.z);
      acc.w = fmaf(w, __uint_as_float(u.y & 0xffff0000u), acc.w);
    }
  }
  int rem = emax - full;
  if (rem > 0) {
    int idx = c0 + li;
    int2 er = (idx < ecnt) ? csr[base + idx] : make_int2(0, 0);
    for (int j = 0; j < rem; ++j) {
      int sl = sg * 16 + j;
      int s = __shfl(er.x, sl);
      float w = __int_as_float(__shfl(er.y, sl));
      uint2 u = a2[(size_t)s * 16 + li];
      acc.x = fmaf(w, __uint_as_float(u.x << 16), acc.x);
      acc.y = fmaf(w, __uint_as_float(u.x & 0xffff0000u), acc.y);
      acc.z = fmaf(w, __uint_as_float(u.y << 16), acc.z);
      acc.w = fmaf(w, __uint_as_float(u.y & 0xffff0000u), acc.w);
    }
  }
  if (valid) {
    acc.x = fmaxf(acc.x, 0.f);
    acc.y = fmaxf(acc.y, 0.f);
    acc.z = fmaxf(acc.z, 0.f);
    acc.w = fmaxf(acc.w, 0.f);
    h4[(size_t)v * 16 + li] = acc;
  }
}

// ---------------------------------------------------------------------------
// fused mean-pool (sorted batch, binary search) + lin1+relu + lin2, wave/graph
__global__ __launch_bounds__(256) void head_kernel(
    const float* __restrict__ h, const int* __restrict__ batch,
    const float* __restrict__ l1w, const float* __restrict__ l1b,
    const float* __restrict__ l2w, const float* __restrict__ l2b,
    float* __restrict__ out)
{
  int g = (blockIdx.x * 256 + threadIdx.x) >> 6;
  int lane = threadIdx.x & 63;
  if (g >= N_GRAPHS) return;
  int lo = 0, hi = N_NODES;
  while (lo < hi) { int mid = (lo + hi) >> 1; if (batch[mid] < g) lo = mid + 1; else hi = mid; }
  int start = lo;
  hi = N_NODES;
  while (lo < hi) { int mid = (lo + hi) >> 1; if (batch[mid] < g + 1) lo = mid + 1; else hi = mid; }
  int end = lo;

  float sum = 0.f;
  for (int v = start; v < end; ++v) sum += h[(size_t)v * 64 + lane];
  float cntf = (float)(end - start);
  float gx = sum / fmaxf(cntf, 1.f);

  float acc = l1b[lane];
  for (int k = 0; k < 64; ++k) {
    float gxk = __shfl(gx, k);
    acc = fmaf(gxk, l1w[k * 64 + lane], acc);
  }
  float t = fmaxf(acc, 0.f);
  float p0 = t * l2w[lane * 3 + 0];
  float p1 = t * l2w[lane * 3 + 1];
  float p2 = t * l2w[lane * 3 + 2];
  for (int off = 32; off > 0; off >>= 1) {
    p0 += __shfl_down(p0, off);
    p1 += __shfl_down(p1, off);
    p2 += __shfl_down(p2, off);
  }
  if (lane == 0) {
    out[g * 3 + 0] = p0 + l2b[0];
    out[g * 3 + 1] = p1 + l2b[1];
    out[g * 3 + 2] = p2 + l2b[2];
  }
}

// ---------------------------------------------------------------------------
extern "C" void kernel_launch(void* const* d_in, const int* in_sizes, int n_in,
                              void* d_out, int out_size, void* d_ws, size_t ws_size,
                              hipStream_t stream)
{
  (void)in_sizes; (void)n_in; (void)out_size; (void)ws_size;
  const float* x     = (const float*)d_in[0];
  const int*   ei    = (const int*)d_in[1];
  const float* ea    = (const float*)d_in[2];
  const int*   batch = (const int*)d_in[3];
  const float* emb_w = (const float*)d_in[4];
  const float* emb_b = (const float*)d_in[5];
  const float* cw1   = (const float*)d_in[6];
  const float* cb1   = (const float*)d_in[7];
  const float* cw2   = (const float*)d_in[8];
  const float* cw3   = (const float*)d_in[9];
  const float* cb3   = (const float*)d_in[10];
  const float* l1w   = (const float*)d_in[11];
  const float* l1b   = (const float*)d_in[12];
  const float* l2w   = (const float*)d_in[13];
  const float* l2b   = (const float*)d_in[14];
  float* out = (float*)d_out;

  char* wsb = (char*)d_ws;
  size_t off = 0;
  auto alloc = [&](size_t bytes) {
    char* p = wsb + off;
    off = (off + bytes + 255) & ~(size_t)255;
    return p;
  };
  float* h       = (float*)alloc(sizeof(float) * (size_t)N_NODES * 64);
  uint2* a_bf    = (uint2*)alloc(sizeof(uint2) * (size_t)N_NODES * 16);
  float* cc_buf  = (float*)alloc(sizeof(float) * (size_t)N_NODES * 64);
  int2*  csr     = (int2*)alloc(sizeof(int2) * (size_t)N_EDGES);
  int*   row_off = (int*)alloc(sizeof(int) * (N_NODES + 1));
  float* degw    = (float*)alloc(sizeof(float) * N_NODES);
  int*   bhist   = (int*)alloc(sizeof(int) * (size_t)G1 * NB);
  int*   tots    = (int*)alloc(sizeof(int) * NB);
  int*   bb      = (int*)alloc(sizeof(int) * (NB + 1));
  // tmp bucket records alias cc_buf: tmp is dead before matvec first writes cc.
  int2* tmp = (int2*)cc_buf;

  embed_kernel<<<(N_NODES * 64 + 255) / 256, 256, 0, stream>>>(x, emb_w, emb_b, h);
  bhist_kernel<<<G1, 256, 0, stream>>>(ei, bhist);
  colscan_kernel<<<NB, 256, 0, stream>>>(bhist, tots);
  bucketscan_kernel<<<1, 512, 0, stream>>>(tots, bb);
  bscatter_kernel<<<G1, 256, 0, stream>>>(ei, ea, bhist, bb, tmp);
  bucket_sort_kernel<<<NB, 256, 0, stream>>>(bb, tmp, csr, row_off, degw);

  int agg_blocks = (N_NODES + 15) / 16;
  int mv_blocks = (N_NODES + 63) / 64;  // 64 nodes/block -> 1563 blocks
  for (int l = 0; l < NLAYER; ++l) {
    matvec3_kernel<<<mv_blocks, 256, 0, stream>>>(
        h, cw1 + l * 4096, cb1 + l * 64, cw2 + l * 4096, cw3 + l * 4096,
        cb3 + l * 64, degw, a_bf, cc_buf);
    agg_kernel<<<agg_blocks, 256, 0, stream>>>(
        a_bf, (const float4*)cc_buf, row_off, csr, (float4*)h);
  }

  head_kernel<<<(N_GRAPHS * 64 + 255) / 256, 256, 0, stream>>>(
      h, batch, l1w, l1b, l2w, l2b, out);
}

// Round 8
// 714.457 us; speedup vs baseline: 2.4306x; 1.0466x over previous
//
#include <hip/hip_runtime.h>

#define N_NODES 100000
#define N_EDGES 3200000
#define N_GRAPHS 1000
#define NLAYER 4
#define NB 391           // coarse buckets: dst>>8, 391*256 = 100096 >= N_NODES
#define G1 782           // edge-pass blocks: 782*4096 >= N_EDGES
#define EPB 4096         // edges per block in edge passes

// round-to-nearest-even f32 -> bf16 (finite inputs)
static __device__ __forceinline__ unsigned f2bf(float f) {
  unsigned u = __float_as_uint(f);
  return (u + 0x7fffu + ((u >> 16) & 1u)) >> 16;
}

__device__ __forceinline__ void fma4(float4& a, float s, const float4& w) {
  a.x = fmaf(s, w.x, a.x);
  a.y = fmaf(s, w.y, a.y);
  a.z = fmaf(s, w.z, a.z);
  a.w = fmaf(s, w.w, a.w);
}

// ---------------------------------------------------------------------------
// h[v][c] = sum_k x[v][k]*emb_w[k][c] + emb_b[c]
__global__ __launch_bounds__(256) void embed_kernel(
    const float* __restrict__ x, const float* __restrict__ emb_w,
    const float* __restrict__ emb_b, float* __restrict__ h)
{
  int t = blockIdx.x * 256 + threadIdx.x;
  if (t >= N_NODES * 64) return;
  int c = t & 63, v = t >> 6;
  float4 xv = ((const float4*)x)[v];
  float acc = emb_b[c];
  acc = fmaf(xv.x, emb_w[0 * 64 + c], acc);
  acc = fmaf(xv.y, emb_w[1 * 64 + c], acc);
  acc = fmaf(xv.z, emb_w[2 * 64 + c], acc);
  acc = fmaf(xv.w, emb_w[3 * 64 + c], acc);
  h[t] = acc;
}

// ---------------------------------------------------------------------------
// A: per-block LDS histogram of coarse bucket (dst>>8). No device atomics.
__global__ __launch_bounds__(256) void bhist_kernel(
    const int* __restrict__ ei, int* __restrict__ bhist)
{
  __shared__ unsigned hist[NB];
  for (int i = threadIdx.x; i < NB; i += 256) hist[i] = 0;
  __syncthreads();
  int base = blockIdx.x * EPB;
#pragma unroll
  for (int i = 0; i < 16; ++i) {
    int e = base + i * 256 + threadIdx.x;
    if (e < N_EDGES) atomicAdd(&hist[((unsigned)ei[N_EDGES + e]) >> 8], 1u);
  }
  __syncthreads();
  for (int i = threadIdx.x; i < NB; i += 256)
    bhist[blockIdx.x * NB + i] = (int)hist[i];
}

// B1: per-bucket column exclusive scan over the G1 block rows (in place);
// column total -> tots[b]
__global__ __launch_bounds__(256) void colscan_kernel(
    int* __restrict__ bhist, int* __restrict__ tots)
{
  int b = blockIdx.x;  // bucket
  __shared__ int s[256];
  __shared__ int carry;
  if (threadIdx.x == 0) carry = 0;
  __syncthreads();
  for (int c0 = 0; c0 < G1; c0 += 256) {
    int g = c0 + threadIdx.x;
    int v = (g < G1) ? bhist[g * NB + b] : 0;
    s[threadIdx.x] = v;
    __syncthreads();
    for (int off = 1; off < 256; off <<= 1) {
      int y = (threadIdx.x >= off) ? s[threadIdx.x - off] : 0;
      __syncthreads();
      s[threadIdx.x] += y;
      __syncthreads();
    }
    if (g < G1) bhist[g * NB + b] = carry + s[threadIdx.x] - v;  // exclusive
    __syncthreads();
    if (threadIdx.x == 0) carry += s[255];
    __syncthreads();
  }
  if (threadIdx.x == 0) tots[b] = carry;
}

// B2: exclusive scan of bucket totals -> bucket base offsets bb[0..NB]
__global__ __launch_bounds__(512) void bucketscan_kernel(
    const int* __restrict__ tots, int* __restrict__ bb)
{
  __shared__ int s[512];
  int x = ((int)threadIdx.x < NB) ? tots[threadIdx.x] : 0;
  s[threadIdx.x] = x;
  __syncthreads();
  for (int off = 1; off < 512; off <<= 1) {
    int y = (threadIdx.x >= off) ? s[threadIdx.x - off] : 0;
    __syncthreads();
    s[threadIdx.x] += y;
    __syncthreads();
  }
  if ((int)threadIdx.x < NB) bb[threadIdx.x] = s[threadIdx.x] - x;
  if (threadIdx.x == 0) bb[NB] = N_EDGES;
}

// C: scatter edges into coarse buckets. LDS cursors only (no device atomics).
// record: x = src | ((dst&255)<<17)   (src < 2^17), y = ew bits (exact f32)
__global__ __launch_bounds__(256) void bscatter_kernel(
    const int* __restrict__ ei, const float* __restrict__ ea,
    const int* __restrict__ bhist, const int* __restrict__ bb,
    int2* __restrict__ tmp)
{
  __shared__ unsigned cur[NB];
  for (int i = threadIdx.x; i < NB; i += 256)
    cur[i] = (unsigned)(bb[i] + bhist[blockIdx.x * NB + i]);
  __syncthreads();
  int base = blockIdx.x * EPB;
#pragma unroll
  for (int i = 0; i < 16; ++i) {
    int e = base + i * 256 + threadIdx.x;
    if (e < N_EDGES) {
      int d = ei[N_EDGES + e];
      int srcv = ei[e];
      float w = ea[e];
      unsigned pos = atomicAdd(&cur[((unsigned)d) >> 8], 1u);
      tmp[pos] = make_int2(srcv | ((d & 255) << 17), __float_as_int(w));
    }
  }
}

// D: one block per bucket: 256-bin LDS counting sort within bucket ->
// final dst-sorted csr (coalesced window), plus row_off and degw for free.
__global__ __launch_bounds__(256) void bucket_sort_kernel(
    const int* __restrict__ bb, const int2* __restrict__ tmp,
    int2* __restrict__ csr, int* __restrict__ row_off, float* __restrict__ degw)
{
  int j = blockIdx.x;
  int b0 = bb[j], b1 = bb[j + 1];
  int nE = b1 - b0;
  __shared__ unsigned hist[256];
  __shared__ float dws[256];
  __shared__ int scanbuf[256];
  __shared__ unsigned cur[256];
  int t = threadIdx.x;
  hist[t] = 0;
  dws[t] = 0.f;
  __syncthreads();
  for (int i = t; i < nE; i += 256) {
    int2 r = tmp[b0 + i];
    int bin = ((unsigned)r.x) >> 17;
    atomicAdd(&hist[bin], 1u);
    atomicAdd(&dws[bin], __int_as_float(r.y));
  }
  __syncthreads();
  int v = (int)hist[t];
  scanbuf[t] = v;
  __syncthreads();
  for (int off = 1; off < 256; off <<= 1) {
    int y = (t >= off) ? scanbuf[t - off] : 0;
    __syncthreads();
    scanbuf[t] += y;
    __syncthreads();
  }
  int myexcl = scanbuf[t] - v;
  cur[t] = (unsigned)myexcl;
  int vnode = (j << 8) + t;
  if (vnode < N_NODES) {
    row_off[vnode] = b0 + myexcl;
    degw[vnode] = dws[t];
  }
  if (j == NB - 1 && t == 0) row_off[N_NODES] = N_EDGES;
  __syncthreads();
  for (int i = t; i < nE; i += 256) {
    int2 r = tmp[b0 + i];
    int bin = ((unsigned)r.x) >> 17;
    unsigned p = atomicAdd(&cur[bin], 1u);
    csr[b0 + (int)p] = make_int2(r.x & 0x1FFFF, r.y);
  }
}

// ---------------------------------------------------------------------------
// fused 3-matvec: 2 nodes per thread sharing every LDS weight read.
// 4 threads/node-slot, 16 channels each, 128 nodes/block, grid = 782.
//   a_out  = bf16(h@W1 + b1)
//   cc_out = b3 + h@W3 - deg_w * (h@W2)   (fp32)
__global__ __launch_bounds__(256) void matvec3_kernel(
    const float* __restrict__ h,
    const float* __restrict__ w1, const float* __restrict__ b1,
    const float* __restrict__ w2,
    const float* __restrict__ w3, const float* __restrict__ b3,
    const float* __restrict__ degw,
    uint2* __restrict__ a_out, float* __restrict__ cc_out)
{
  // LDS: [0..1023]=W2, [1024..2047]=W3, [2048..3071]=W1 (float4 granules)
  __shared__ float4 ws[3 * 1024];
  int tid = threadIdx.x;
  {
    const float4* w1v = (const float4*)w1;
    const float4* w2v = (const float4*)w2;
    const float4* w3v = (const float4*)w3;
    for (int i = tid; i < 1024; i += 256) {
      ws[i] = w2v[i];
      ws[1024 + i] = w3v[i];
      ws[2048 + i] = w1v[i];
    }
  }
  __syncthreads();

  int p = tid >> 2;          // node slot 0..63
  int cg = tid & 3;          // channel group: channels cg*16 .. cg*16+15
  int v0 = blockIdx.x * 128 + p;
  int v1 = v0 + 64;
  bool val0 = v0 < N_NODES, val1 = v1 < N_NODES;
  int v0c = val0 ? v0 : 0;
  int v1c = val1 ? v1 : 0;
  const float4* hp0 = (const float4*)(h + (size_t)v0c * 64);
  const float4* hp1 = (const float4*)(h + (size_t)v1c * 64);
  float dw0 = degw[v0c], dw1 = degw[v1c];
  float4 acc0[4], acc1[4];

  // h re-read from global each phase (L1/L2-resident) to keep VGPRs low.
  auto phase = [&](int base) {
#pragma unroll 4
    for (int k4 = 0; k4 < 16; ++k4) {
      float4 hk0 = hp0[k4];
      float4 hk1 = hp1[k4];
      const float4* wr = &ws[base + k4 * 64 + cg * 4];
#pragma unroll
      for (int j = 0; j < 4; ++j) {
        float4 wa = wr[j], wb = wr[16 + j], wc = wr[32 + j], wd = wr[48 + j];
        fma4(acc0[j], hk0.x, wa); fma4(acc0[j], hk0.y, wb);
        fma4(acc0[j], hk0.z, wc); fma4(acc0[j], hk0.w, wd);
        fma4(acc1[j], hk1.x, wa); fma4(acc1[j], hk1.y, wb);
        fma4(acc1[j], hk1.z, wc); fma4(acc1[j], hk1.w, wd);
      }
    }
  };

  // ---- cc: acc = h@W2; *= -dw; += h@W3; += b3; store fp32 ----
#pragma unroll
  for (int j = 0; j < 4; ++j) {
    acc0[j] = make_float4(0.f, 0.f, 0.f, 0.f);
    acc1[j] = make_float4(0.f, 0.f, 0.f, 0.f);
  }
  phase(0);
#pragma unroll
  for (int j = 0; j < 4; ++j) {
    acc0[j].x *= -dw0; acc0[j].y *= -dw0; acc0[j].z *= -dw0; acc0[j].w *= -dw0;
    acc1[j].x *= -dw1; acc1[j].y *= -dw1; acc1[j].z *= -dw1; acc1[j].w *= -dw1;
  }
  phase(1024);
  {
    const float4* b3q = (const float4*)b3;
    float4* ccp0 = (float4*)(cc_out + (size_t)v0c * 64);
    float4* ccp1 = (float4*)(cc_out + (size_t)v1c * 64);
#pragma unroll
    for (int j = 0; j < 4; ++j) {
      float4 bb3 = b3q[cg * 4 + j];
      if (val0) {
        float4 o = acc0[j];
        o.x += bb3.x; o.y += bb3.y; o.z += bb3.z; o.w += bb3.w;
        ccp0[cg * 4 + j] = o;
      }
      if (val1) {
        float4 o = acc1[j];
        o.x += bb3.x; o.y += bb3.y; o.z += bb3.z; o.w += bb3.w;
        ccp1[cg * 4 + j] = o;
      }
    }
  }

  // ---- a: acc = b1 + h@W1; store bf16 ----
  {
    const float4* b1q = (const float4*)b1;
#pragma unroll
    for (int j = 0; j < 4; ++j) {
      float4 bb1 = b1q[cg * 4 + j];
      acc0[j] = bb1;
      acc1[j] = bb1;
    }
  }
  phase(2048);
  {
    uint2* ap0 = a_out + (size_t)v0c * 16;
    uint2* ap1 = a_out + (size_t)v1c * 16;
#pragma unroll
    for (int j = 0; j < 4; ++j) {
      if (val0) {
        float4 o = acc0[j];
        uint2 pk;
        pk.x = f2bf(o.x) | (f2bf(o.y) << 16);
        pk.y = f2bf(o.z) | (f2bf(o.w) << 16);
        ap0[cg * 4 + j] = pk;
      }
      if (val1) {
        float4 o = acc1[j];
        uint2 pk;
        pk.x = f2bf(o.x) | (f2bf(o.y) << 16);
        pk.y = f2bf(o.z) | (f2bf(o.w) << 16);
        ap1[cg * 4 + j] = pk;
      }
    }
  }
}

// ---------------------------------------------------------------------------
// h_new[v] = relu(cc[v] + sum_{e in CSR(v)} ew_e * a[src_e])
// 4 nodes/wave, 16 lanes per node; a-rows bf16 (128 B).
__global__ __launch_bounds__(256) void agg_kernel(
    const uint2* __restrict__ a2, const float4* __restrict__ cc4,
    const int* __restrict__ row_off, const int2* __restrict__ csr,
    float4* __restrict__ h4)
{
  int wave = (blockIdx.x * 256 + threadIdx.x) >> 6;
  int lane = threadIdx.x & 63;
  int sg = lane >> 4;
  int li = lane & 15;
  int v = wave * 4 + sg;
  bool valid = v < N_NODES;
  int vc = valid ? v : N_NODES - 1;
  int base = row_off[vc];
  int ecnt = valid ? (row_off[vc + 1] - base) : 0;
  int emax = ecnt;
  emax = max(emax, __shfl_xor(emax, 16));
  emax = max(emax, __shfl_xor(emax, 32));

  float4 acc = valid ? cc4[(size_t)vc * 16 + li] : make_float4(0.f, 0.f, 0.f, 0.f);

  int full = emax & ~15;
  int c0 = 0;
  for (; c0 < full; c0 += 16) {
    int idx = c0 + li;
    int2 er = (idx < ecnt) ? csr[base + idx] : make_int2(0, 0);
#pragma unroll
    for (int j = 0; j < 16; ++j) {
      int sl = sg * 16 + j;
      int s = __shfl(er.x, sl);
      float w = __int_as_float(__shfl(er.y, sl));
      uint2 u = a2[(size_t)s * 16 + li];
      acc.x = fmaf(w, __uint_as_float(u.x << 16), acc.x);
      acc.y = fmaf(w, __uint_as_float(u.x & 0xffff0000u), acc.y);
      acc.z = fmaf(w, __uint_as_float(u.y << 16), acc.z);
      acc.w = fmaf(w, __uint_as_float(u.y & 0xffff0000u), acc.w);
    }
  }
  int rem = emax - full;
  if (rem > 0) {
    int idx = c0 + li;
    int2 er = (idx < ecnt) ? csr[base + idx] : make_int2(0, 0);
    for (int j = 0; j < rem; ++j) {
      int sl = sg * 16 + j;
      int s = __shfl(er.x, sl);
      float w = __int_as_float(__shfl(er.y, sl));
      uint2 u = a2[(size_t)s * 16 + li];
      acc.x = fmaf(w, __uint_as_float(u.x << 16), acc.x);
      acc.y = fmaf(w, __uint_as_float(u.x & 0xffff0000u), acc.y);
      acc.z = fmaf(w, __uint_as_float(u.y << 16), acc.z);
      acc.w = fmaf(w, __uint_as_float(u.y & 0xffff0000u), acc.w);
    }
  }
  if (valid) {
    acc.x = fmaxf(acc.x, 0.f);
    acc.y = fmaxf(acc.y, 0.f);
    acc.z = fmaxf(acc.z, 0.f);
    acc.w = fmaxf(acc.w, 0.f);
    h4[(size_t)v * 16 + li] = acc;
  }
}

// ---------------------------------------------------------------------------
// fused mean-pool (sorted batch, binary search) + lin1+relu + lin2, wave/graph
__global__ __launch_bounds__(256) void head_kernel(
    const float* __restrict__ h, const int* __restrict__ batch,
    const float* __restrict__ l1w, const float* __restrict__ l1b,
    const float* __restrict__ l2w, const float* __restrict__ l2b,
    float* __restrict__ out)
{
  int g = (blockIdx.x * 256 + threadIdx.x) >> 6;
  int lane = threadIdx.x & 63;
  if (g >= N_GRAPHS) return;
  int lo = 0, hi = N_NODES;
  while (lo < hi) { int mid = (lo + hi) >> 1; if (batch[mid] < g) lo = mid + 1; else hi = mid; }
  int start = lo;
  hi = N_NODES;
  while (lo < hi) { int mid = (lo + hi) >> 1; if (batch[mid] < g + 1) lo = mid + 1; else hi = mid; }
  int end = lo;

  float sum = 0.f;
  for (int v = start; v < end; ++v) sum += h[(size_t)v * 64 + lane];
  float cntf = (float)(end - start);
  float gx = sum / fmaxf(cntf, 1.f);

  float acc = l1b[lane];
  for (int k = 0; k < 64; ++k) {
    float gxk = __shfl(gx, k);
    acc = fmaf(gxk, l1w[k * 64 + lane], acc);
  }
  float t = fmaxf(acc, 0.f);
  float p0 = t * l2w[lane * 3 + 0];
  float p1 = t * l2w[lane * 3 + 1];
  float p2 = t * l2w[lane * 3 + 2];
  for (int off = 32; off > 0; off >>= 1) {
    p0 += __shfl_down(p0, off);
    p1 += __shfl_down(p1, off);
    p2 += __shfl_down(p2, off);
  }
  if (lane == 0) {
    out[g * 3 + 0] = p0 + l2b[0];
    out[g * 3 + 1] = p1 + l2b[1];
    out[g * 3 + 2] = p2 + l2b[2];
  }
}

// ---------------------------------------------------------------------------
extern "C" void kernel_launch(void* const* d_in, const int* in_sizes, int n_in,
                              void* d_out, int out_size, void* d_ws, size_t ws_size,
                              hipStream_t stream)
{
  (void)in_sizes; (void)n_in; (void)out_size; (void)ws_size;
  const float* x     = (const float*)d_in[0];
  const int*   ei    = (const int*)d_in[1];
  const float* ea    = (const float*)d_in[2];
  const int*   batch = (const int*)d_in[3];
  const float* emb_w = (const float*)d_in[4];
  const float* emb_b = (const float*)d_in[5];
  const float* cw1   = (const float*)d_in[6];
  const float* cb1   = (const float*)d_in[7];
  const float* cw2   = (const float*)d_in[8];
  const float* cw3   = (const float*)d_in[9];
  const float* cb3   = (const float*)d_in[10];
  const float* l1w   = (const float*)d_in[11];
  const float* l1b   = (const float*)d_in[12];
  const float* l2w   = (const float*)d_in[13];
  const float* l2b   = (const float*)d_in[14];
  float* out = (float*)d_out;

  char* wsb = (char*)d_ws;
  size_t off = 0;
  auto alloc = [&](size_t bytes) {
    char* p = wsb + off;
    off = (off + bytes + 255) & ~(size_t)255;
    return p;
  };
  float* h       = (float*)alloc(sizeof(float) * (size_t)N_NODES * 64);
  uint2* a_bf    = (uint2*)alloc(sizeof(uint2) * (size_t)N_NODES * 16);
  float* cc_buf  = (float*)alloc(sizeof(float) * (size_t)N_NODES * 64);
  int2*  csr     = (int2*)alloc(sizeof(int2) * (size_t)N_EDGES);
  int*   row_off = (int*)alloc(sizeof(int) * (N_NODES + 1));
  float* degw    = (float*)alloc(sizeof(float) * N_NODES);
  int*   bhist   = (int*)alloc(sizeof(int) * (size_t)G1 * NB);
  int*   tots    = (int*)alloc(sizeof(int) * NB);
  int*   bb      = (int*)alloc(sizeof(int) * (NB + 1));
  // tmp bucket records alias cc_buf: tmp is dead before matvec first writes cc.
  int2* tmp = (int2*)cc_buf;

  embed_kernel<<<(N_NODES * 64 + 255) / 256, 256, 0, stream>>>(x, emb_w, emb_b, h);
  bhist_kernel<<<G1, 256, 0, stream>>>(ei, bhist);
  colscan_kernel<<<NB, 256, 0, stream>>>(bhist, tots);
  bucketscan_kernel<<<1, 512, 0, stream>>>(tots, bb);
  bscatter_kernel<<<G1, 256, 0, stream>>>(ei, ea, bhist, bb, tmp);
  bucket_sort_kernel<<<NB, 256, 0, stream>>>(bb, tmp, csr, row_off, degw);

  int agg_blocks = (N_NODES + 15) / 16;
  int mv_blocks = (N_NODES + 127) / 128;  // 128 nodes/block -> 782 blocks
  for (int l = 0; l < NLAYER; ++l) {
    matvec3_kernel<<<mv_blocks, 256, 0, stream>>>(
        h, cw1 + l * 4096, cb1 + l * 64, cw2 + l * 4096, cw3 + l * 4096,
        cb3 + l * 64, degw, a_bf, cc_buf);
    agg_kernel<<<agg_blocks, 256, 0, stream>>>(
        a_bf, (const float4*)cc_buf, row_off, csr, (float4*)h);
  }

  head_kernel<<<(N_GRAPHS * 64 + 255) / 256, 256, 0, stream>>>(
      h, batch, l1w, l1b, l2w, l2b, out);
}

// Round 10
// 711.385 us; speedup vs baseline: 2.4411x; 1.0043x over previous
//
#include <hip/hip_runtime.h>

#define N_NODES 100000
#define N_EDGES 3200000
#define N_GRAPHS 1000
#define NLAYER 4
#define NB 391           // coarse buckets: dst>>8, 391*256 = 100096 >= N_NODES
#define G1 782           // edge-pass blocks: 782*4096 >= N_EDGES
#define EPB 4096         // edges per block in edge passes
#define PCAP 16384       // bucket_sort perm capacity (mean bucket 8184, sd ~90)

// round-to-nearest-even f32 -> bf16 (finite inputs)
static __device__ __forceinline__ unsigned f2bf(float f) {
  unsigned u = __float_as_uint(f);
  return (u + 0x7fffu + ((u >> 16) & 1u)) >> 16;
}

__device__ __forceinline__ void fma4(float4& a, float s, const float4& w) {
  a.x = fmaf(s, w.x, a.x);
  a.y = fmaf(s, w.y, a.y);
  a.z = fmaf(s, w.z, a.z);
  a.w = fmaf(s, w.w, a.w);
}

// ---------------------------------------------------------------------------
// h[v][c] = sum_k x[v][k]*emb_w[k][c] + emb_b[c]
__global__ __launch_bounds__(256) void embed_kernel(
    const float* __restrict__ x, const float* __restrict__ emb_w,
    const float* __restrict__ emb_b, float* __restrict__ h)
{
  int t = blockIdx.x * 256 + threadIdx.x;
  if (t >= N_NODES * 64) return;
  int c = t & 63, v = t >> 6;
  float4 xv = ((const float4*)x)[v];
  float acc = emb_b[c];
  acc = fmaf(xv.x, emb_w[0 * 64 + c], acc);
  acc = fmaf(xv.y, emb_w[1 * 64 + c], acc);
  acc = fmaf(xv.z, emb_w[2 * 64 + c], acc);
  acc = fmaf(xv.w, emb_w[3 * 64 + c], acc);
  h[t] = acc;
}

// ---------------------------------------------------------------------------
// A: per-block LDS histogram of coarse bucket (dst>>8). No device atomics.
__global__ __launch_bounds__(256) void bhist_kernel(
    const int* __restrict__ ei, int* __restrict__ bhist)
{
  __shared__ unsigned hist[NB];
  for (int i = threadIdx.x; i < NB; i += 256) hist[i] = 0;
  __syncthreads();
  int base = blockIdx.x * EPB;
#pragma unroll
  for (int i = 0; i < 16; ++i) {
    int e = base + i * 256 + threadIdx.x;
    if (e < N_EDGES) atomicAdd(&hist[((unsigned)ei[N_EDGES + e]) >> 8], 1u);
  }
  __syncthreads();
  for (int i = threadIdx.x; i < NB; i += 256)
    bhist[blockIdx.x * NB + i] = (int)hist[i];
}

// B1: per-bucket column exclusive scan over the G1 block rows (in place);
// column total -> tots[b]
__global__ __launch_bounds__(256) void colscan_kernel(
    int* __restrict__ bhist, int* __restrict__ tots)
{
  int b = blockIdx.x;  // bucket
  __shared__ int s[256];
  __shared__ int carry;
  if (threadIdx.x == 0) carry = 0;
  __syncthreads();
  for (int c0 = 0; c0 < G1; c0 += 256) {
    int g = c0 + threadIdx.x;
    int v = (g < G1) ? bhist[g * NB + b] : 0;
    s[threadIdx.x] = v;
    __syncthreads();
    for (int off = 1; off < 256; off <<= 1) {
      int y = (threadIdx.x >= off) ? s[threadIdx.x - off] : 0;
      __syncthreads();
      s[threadIdx.x] += y;
      __syncthreads();
    }
    if (g < G1) bhist[g * NB + b] = carry + s[threadIdx.x] - v;  // exclusive
    __syncthreads();
    if (threadIdx.x == 0) carry += s[255];
    __syncthreads();
  }
  if (threadIdx.x == 0) tots[b] = carry;
}

// B2: exclusive scan of bucket totals -> bucket base offsets bb[0..NB]
__global__ __launch_bounds__(512) void bucketscan_kernel(
    const int* __restrict__ tots, int* __restrict__ bb)
{
  __shared__ int s[512];
  int x = ((int)threadIdx.x < NB) ? tots[threadIdx.x] : 0;
  s[threadIdx.x] = x;
  __syncthreads();
  for (int off = 1; off < 512; off <<= 1) {
    int y = (threadIdx.x >= off) ? s[threadIdx.x - off] : 0;
    __syncthreads();
    s[threadIdx.x] += y;
    __syncthreads();
  }
  if ((int)threadIdx.x < NB) bb[threadIdx.x] = s[threadIdx.x] - x;
  if (threadIdx.x == 0) bb[NB] = N_EDGES;
}

// C: scatter edges into coarse buckets, LDS-staged for coalesced writes.
// record: x = src | ((dst&255)<<17)   (src < 2^17), y = ew bits (exact f32)
// LDS: 32K stage + 8K bid + ~5.7K control = ~46 KB.
__global__ __launch_bounds__(256) void bscatter_kernel(
    const int* __restrict__ ei, const float* __restrict__ ea,
    const int* __restrict__ bhist, const int* __restrict__ bb,
    int2* __restrict__ tmp)
{
  __shared__ unsigned hist[NB];
  __shared__ int lbase[NB];
  __shared__ unsigned cur[NB];
  __shared__ int2 stage[EPB];          // 32 KB
  __shared__ unsigned short bid[EPB];  // 8 KB
  __shared__ int carry;
  __shared__ int sbuf[256];
  int tid = threadIdx.x;
  int base = blockIdx.x * EPB;

  for (int i = tid; i < NB; i += 256) hist[i] = 0;
  if (tid == 0) carry = 0;
  __syncthreads();

  // pass 1: local bucket histogram
#pragma unroll
  for (int i = 0; i < 16; ++i) {
    int e = base + i * 256 + tid;
    if (e < N_EDGES) atomicAdd(&hist[((unsigned)ei[N_EDGES + e]) >> 8], 1u);
  }
  __syncthreads();

  // local exclusive scan over NB bins (2 chunks of 256)
  for (int c0 = 0; c0 < NB; c0 += 256) {
    int g = c0 + tid;
    int v = (g < NB) ? (int)hist[g] : 0;
    sbuf[tid] = v;
    __syncthreads();
    for (int off = 1; off < 256; off <<= 1) {
      int y = (tid >= off) ? sbuf[tid - off] : 0;
      __syncthreads();
      sbuf[tid] += y;
      __syncthreads();
    }
    if (g < NB) {
      int ex = carry + sbuf[tid] - v;
      lbase[g] = ex;
      cur[g] = (unsigned)ex;
    }
    __syncthreads();
    if (tid == 0) carry += sbuf[255];
    __syncthreads();
  }

  // pass 2: place records at block-local sorted positions in LDS
#pragma unroll
  for (int i = 0; i < 16; ++i) {
    int e = base + i * 256 + tid;
    if (e < N_EDGES) {
      int d = ei[N_EDGES + e];
      unsigned bkt = ((unsigned)d) >> 8;
      unsigned lp = atomicAdd(&cur[bkt], 1u);
      stage[lp] = make_int2(ei[e] | ((d & 255) << 17), __float_as_int(ea[e]));
      bid[lp] = (unsigned short)bkt;
    }
  }
  __syncthreads();

  // pass 3: ordered write-out; consecutive i in a run -> consecutive gpos
  int nE = min(EPB, N_EDGES - base);
  for (int i = tid; i < nE; i += 256) {
    int bkt = (int)bid[i];
    int gpos = bb[bkt] + bhist[blockIdx.x * NB + bkt] + (i - lbase[bkt]);
    tmp[gpos] = stage[i];
  }
}

// D: one block per bucket: 256-bin LDS counting sort within bucket.
// Stages only a u16 permutation (perm[p]=i), then streams csr contiguously,
// gathering tmp[b0+perm[q]] from the L2-resident 64 KB window.
// LDS: 32K perm + ~5K control = ~37 KB. Also emits row_off and degw.
__global__ __launch_bounds__(256) void bucket_sort_kernel(
    const int* __restrict__ bb, const int2* __restrict__ tmp,
    int2* __restrict__ csr, int* __restrict__ row_off, float* __restrict__ degw)
{
  int j = blockIdx.x;
  int b0 = bb[j], b1 = bb[j + 1];
  int nE = b1 - b0;
  __shared__ unsigned hist[256];
  __shared__ float dws[256];
  __shared__ int scanbuf[256];
  __shared__ unsigned cur[256];
  __shared__ unsigned short perm[PCAP];  // 32 KB
  int t = threadIdx.x;
  hist[t] = 0;
  dws[t] = 0.f;
  __syncthreads();
  for (int i = t; i < nE; i += 256) {
    int2 r = tmp[b0 + i];
    int bin = ((unsigned)r.x) >> 17;
    atomicAdd(&hist[bin], 1u);
    atomicAdd(&dws[bin], __int_as_float(r.y));
  }
  __syncthreads();
  int v = (int)hist[t];
  scanbuf[t] = v;
  __syncthreads();
  for (int off = 1; off < 256; off <<= 1) {
    int y = (t >= off) ? scanbuf[t - off] : 0;
    __syncthreads();
    scanbuf[t] += y;
    __syncthreads();
  }
  int myexcl = scanbuf[t] - v;
  cur[t] = (unsigned)myexcl;
  int vnode = (j << 8) + t;
  if (vnode < N_NODES) {
    row_off[vnode] = b0 + myexcl;
    degw[vnode] = dws[t];
  }
  if (j == NB - 1 && t == 0) row_off[N_NODES] = N_EDGES;
  __syncthreads();

  if (nE <= PCAP) {
    // build permutation in LDS, then contiguous streaming write
    for (int i = t; i < nE; i += 256) {
      int2 r = tmp[b0 + i];
      int bin = ((unsigned)r.x) >> 17;
      unsigned p = atomicAdd(&cur[bin], 1u);
      perm[p] = (unsigned short)i;
    }
    __syncthreads();
    for (int q = t; q < nE; q += 256) {
      int2 r = tmp[b0 + (int)perm[q]];
      csr[b0 + q] = make_int2(r.x & 0x1FFFF, r.y);
    }
  } else {
    // statistical never-path; correctness fallback (direct scatter)
    for (int i = t; i < nE; i += 256) {
      int2 r = tmp[b0 + i];
      int bin = ((unsigned)r.x) >> 17;
      unsigned p = atomicAdd(&cur[bin], 1u);
      csr[b0 + (int)p] = make_int2(r.x & 0x1FFFF, r.y);
    }
  }
}

// ---------------------------------------------------------------------------
// fused 3-matvec: 2 nodes per thread sharing every LDS weight read.
// 4 threads/node-slot, 16 channels each, 128 nodes/block, grid = 782.
//   a_out  = bf16(h@W1 + b1)
//   cc_out = b3 + h@W3 - deg_w * (h@W2)   (fp32)
__global__ __launch_bounds__(256) void matvec3_kernel(
    const float* __restrict__ h,
    const float* __restrict__ w1, const float* __restrict__ b1,
    const float* __restrict__ w2,
    const float* __restrict__ w3, const float* __restrict__ b3,
    const float* __restrict__ degw,
    uint2* __restrict__ a_out, float* __restrict__ cc_out)
{
  // LDS: [0..1023]=W2, [1024..2047]=W3, [2048..3071]=W1 (float4 granules)
  __shared__ float4 ws[3 * 1024];
  int tid = threadIdx.x;
  {
    const float4* w1v = (const float4*)w1;
    const float4* w2v = (const float4*)w2;
    const float4* w3v = (const float4*)w3;
    for (int i = tid; i < 1024; i += 256) {
      ws[i] = w2v[i];
      ws[1024 + i] = w3v[i];
      ws[2048 + i] = w1v[i];
    }
  }
  __syncthreads();

  int p = tid >> 2;          // node slot 0..63
  int cg = tid & 3;          // channel group: channels cg*16 .. cg*16+15
  int v0 = blockIdx.x * 128 + p;
  int v1 = v0 + 64;
  bool val0 = v0 < N_NODES, val1 = v1 < N_NODES;
  int v0c = val0 ? v0 : 0;
  int v1c = val1 ? v1 : 0;
  const float4* hp0 = (const float4*)(h + (size_t)v0c * 64);
  const float4* hp1 = (const float4*)(h + (size_t)v1c * 64);
  float dw0 = degw[v0c], dw1 = degw[v1c];
  float4 acc0[4], acc1[4];

  auto phase = [&](int base) {
#pragma unroll 4
    for (int k4 = 0; k4 < 16; ++k4) {
      float4 hk0 = hp0[k4];
      float4 hk1 = hp1[k4];
      const float4* wr = &ws[base + k4 * 64 + cg * 4];
#pragma unroll
      for (int j = 0; j < 4; ++j) {
        float4 wa = wr[j], wb = wr[16 + j], wc = wr[32 + j], wd = wr[48 + j];
        fma4(acc0[j], hk0.x, wa); fma4(acc0[j], hk0.y, wb);
        fma4(acc0[j], hk0.z, wc); fma4(acc0[j], hk0.w, wd);
        fma4(acc1[j], hk1.x, wa); fma4(acc1[j], hk1.y, wb);
        fma4(acc1[j], hk1.z, wc); fma4(acc1[j], hk1.w, wd);
      }
    }
  };

  // ---- cc: acc = h@W2; *= -dw; += h@W3; += b3; store fp32 ----
#pragma unroll
  for (int j = 0; j < 4; ++j) {
    acc0[j] = make_float4(0.f, 0.f, 0.f, 0.f);
    acc1[j] = make_float4(0.f, 0.f, 0.f, 0.f);
  }
  phase(0);
#pragma unroll
  for (int j = 0; j < 4; ++j) {
    acc0[j].x *= -dw0; acc0[j].y *= -dw0; acc0[j].z *= -dw0; acc0[j].w *= -dw0;
    acc1[j].x *= -dw1; acc1[j].y *= -dw1; acc1[j].z *= -dw1; acc1[j].w *= -dw1;
  }
  phase(1024);
  {
    const float4* b3q = (const float4*)b3;
    float4* ccp0 = (float4*)(cc_out + (size_t)v0c * 64);
    float4* ccp1 = (float4*)(cc_out + (size_t)v1c * 64);
#pragma unroll
    for (int j = 0; j < 4; ++j) {
      float4 bb3 = b3q[cg * 4 + j];
      if (val0) {
        float4 o = acc0[j];
        o.x += bb3.x; o.y += bb3.y; o.z += bb3.z; o.w += bb3.w;
        ccp0[cg * 4 + j] = o;
      }
      if (val1) {
        float4 o = acc1[j];
        o.x += bb3.x; o.y += bb3.y; o.z += bb3.z; o.w += bb3.w;
        ccp1[cg * 4 + j] = o;
      }
    }
  }

  // ---- a: acc = b1 + h@W1; store bf16 ----
  {
    const float4* b1q = (const float4*)b1;
#pragma unroll
    for (int j = 0; j < 4; ++j) {
      float4 bb1 = b1q[cg * 4 + j];
      acc0[j] = bb1;
      acc1[j] = bb1;
    }
  }
  phase(2048);
  {
    uint2* ap0 = a_out + (size_t)v0c * 16;
    uint2* ap1 = a_out + (size_t)v1c * 16;
#pragma unroll
    for (int j = 0; j < 4; ++j) {
      if (val0) {
        float4 o = acc0[j];
        uint2 pk;
        pk.x = f2bf(o.x) | (f2bf(o.y) << 16);
        pk.y = f2bf(o.z) | (f2bf(o.w) << 16);
        ap0[cg * 4 + j] = pk;
      }
      if (val1) {
        float4 o = acc1[j];
        uint2 pk;
        pk.x = f2bf(o.x) | (f2bf(o.y) << 16);
        pk.y = f2bf(o.z) | (f2bf(o.w) << 16);
        ap1[cg * 4 + j] = pk;
      }
    }
  }
}

// ---------------------------------------------------------------------------
// h_new[v] = relu(cc[v] + sum_{e in CSR(v)} ew_e * a[src_e])
// 4 nodes/wave, 16 lanes per node; a-rows bf16 (128 B).
__global__ __launch_bounds__(256) void agg_kernel(
    const uint2* __restrict__ a2, const float4* __restrict__ cc4,
    const int* __restrict__ row_off, const int2* __restrict__ csr,
    float4* __restrict__ h4)
{
  int wave = (blockIdx.x * 256 + threadIdx.x) >> 6;
  int lane = threadIdx.x & 63;
  int sg = lane >> 4;
  int li = lane & 15;
  int v = wave * 4 + sg;
  bool valid = v < N_NODES;
  int vc = valid ? v : N_NODES - 1;
  int base = row_off[vc];
  int ecnt = valid ? (row_off[vc + 1] - base) : 0;
  int emax = ecnt;
  emax = max(emax, __shfl_xor(emax, 16));
  emax = max(emax, __shfl_xor(emax, 32));

  float4 acc = valid ? cc4[(size_t)vc * 16 + li] : make_float4(0.f, 0.f, 0.f, 0.f);

  int full = emax & ~15;
  int c0 = 0;
  for (; c0 < full; c0 += 16) {
    int idx = c0 + li;
    int2 er = (idx < ecnt) ? csr[base + idx] : make_int2(0, 0);
#pragma unroll
    for (int j = 0; j < 16; ++j) {
      int sl = sg * 16 + j;
      int s = __shfl(er.x, sl);
      float w = __int_as_float(__shfl(er.y, sl));
      uint2 u = a2[(size_t)s * 16 + li];
      acc.x = fmaf(w, __uint_as_float(u.x << 16), acc.x);
      acc.y = fmaf(w, __uint_as_float(u.x & 0xffff0000u), acc.y);
      acc.z = fmaf(w, __uint_as_float(u.y << 16), acc.z);
      acc.w = fmaf(w, __uint_as_float(u.y & 0xffff0000u), acc.w);
    }
  }
  int rem = emax - full;
  if (rem > 0) {
    int idx = c0 + li;
    int2 er = (idx < ecnt) ? csr[base + idx] : make_int2(0, 0);
    for (int j = 0; j < rem; ++j) {
      int sl = sg * 16 + j;
      int s = __shfl(er.x, sl);
      float w = __int_as_float(__shfl(er.y, sl));
      uint2 u = a2[(size_t)s * 16 + li];
      acc.x = fmaf(w, __uint_as_float(u.x << 16), acc.x);
      acc.y = fmaf(w, __uint_as_float(u.x & 0xffff0000u), acc.y);
      acc.z = fmaf(w, __uint_as_float(u.y << 16), acc.z);
      acc.w = fmaf(w, __uint_as_float(u.y & 0xffff0000u), acc.w);
    }
  }
  if (valid) {
    acc.x = fmaxf(acc.x, 0.f);
    acc.y = fmaxf(acc.y, 0.f);
    acc.z = fmaxf(acc.z, 0.f);
    acc.w = fmaxf(acc.w, 0.f);
    h4[(size_t)v * 16 + li] = acc;
  }
}

// ---------------------------------------------------------------------------
// fused mean-pool (sorted batch, binary search) + lin1+relu + lin2, wave/graph
__global__ __launch_bounds__(256) void head_kernel(
    const float* __restrict__ h, const int* __restrict__ batch,
    const float* __restrict__ l1w, const float* __restrict__ l1b,
    const float* __restrict__ l2w, const float* __restrict__ l2b,
    float* __restrict__ out)
{
  int g = (blockIdx.x * 256 + threadIdx.x) >> 6;
  int lane = threadIdx.x & 63;
  if (g >= N_GRAPHS) return;
  int lo = 0, hi = N_NODES;
  while (lo < hi) { int mid = (lo + hi) >> 1; if (batch[mid] < g) lo = mid + 1; else hi = mid; }
  int start = lo;
  hi = N_NODES;
  while (lo < hi) { int mid = (lo + hi) >> 1; if (batch[mid] < g + 1) lo = mid + 1; else hi = mid; }
  int end = lo;

  float sum = 0.f;
  for (int v = start; v < end; ++v) sum += h[(size_t)v * 64 + lane];
  float cntf = (float)(end - start);
  float gx = sum / fmaxf(cntf, 1.f);

  float acc = l1b[lane];
  for (int k = 0; k < 64; ++k) {
    float gxk = __shfl(gx, k);
    acc = fmaf(gxk, l1w[k * 64 + lane], acc);
  }
  float t = fmaxf(acc, 0.f);
  float p0 = t * l2w[lane * 3 + 0];
  float p1 = t * l2w[lane * 3 + 1];
  float p2 = t * l2w[lane * 3 + 2];
  for (int off = 32; off > 0; off >>= 1) {
    p0 += __shfl_down(p0, off);
    p1 += __shfl_down(p1, off);
    p2 += __shfl_down(p2, off);
  }
  if (lane == 0) {
    out[g * 3 + 0] = p0 + l2b[0];
    out[g * 3 + 1] = p1 + l2b[1];
    out[g * 3 + 2] = p2 + l2b[2];
  }
}

// ---------------------------------------------------------------------------
extern "C" void kernel_launch(void* const* d_in, const int* in_sizes, int n_in,
                              void* d_out, int out_size, void* d_ws, size_t ws_size,
                              hipStream_t stream)
{
  (void)in_sizes; (void)n_in; (void)out_size; (void)ws_size;
  const float* x     = (const float*)d_in[0];
  const int*   ei    = (const int*)d_in[1];
  const float* ea    = (const float*)d_in[2];
  const int*   batch = (const int*)d_in[3];
  const float* emb_w = (const float*)d_in[4];
  const float* emb_b = (const float*)d_in[5];
  const float* cw1   = (const float*)d_in[6];
  const float* cb1   = (const float*)d_in[7];
  const float* cw2   = (const float*)d_in[8];
  const float* cw3   = (const float*)d_in[9];
  const float* cb3   = (const float*)d_in[10];
  const float* l1w   = (const float*)d_in[11];
  const float* l1b   = (const float*)d_in[12];
  const float* l2w   = (const float*)d_in[13];
  const float* l2b   = (const float*)d_in[14];
  float* out = (float*)d_out;

  char* wsb = (char*)d_ws;
  size_t off = 0;
  auto alloc = [&](size_t bytes) {
    char* p = wsb + off;
    off = (off + bytes + 255) & ~(size_t)255;
    return p;
  };
  float* h       = (float*)alloc(sizeof(float) * (size_t)N_NODES * 64);
  uint2* a_bf    = (uint2*)alloc(sizeof(uint2) * (size_t)N_NODES * 16);
  float* cc_buf  = (float*)alloc(sizeof(float) * (size_t)N_NODES * 64);
  int2*  csr     = (int2*)alloc(sizeof(int2) * (size_t)N_EDGES);
  int*   row_off = (int*)alloc(sizeof(int) * (N_NODES + 1));
  float* degw    = (float*)alloc(sizeof(float) * N_NODES);
  int*   bhist   = (int*)alloc(sizeof(int) * (size_t)G1 * NB);
  int*   tots    = (int*)alloc(sizeof(int) * NB);
  int*   bb      = (int*)alloc(sizeof(int) * (NB + 1));
  // tmp bucket records alias cc_buf: tmp is dead before matvec first writes cc.
  int2* tmp = (int2*)cc_buf;

  embed_kernel<<<(N_NODES * 64 + 255) / 256, 256, 0, stream>>>(x, emb_w, emb_b, h);
  bhist_kernel<<<G1, 256, 0, stream>>>(ei, bhist);
  colscan_kernel<<<NB, 256, 0, stream>>>(bhist, tots);
  bucketscan_kernel<<<1, 512, 0, stream>>>(tots, bb);
  bscatter_kernel<<<G1, 256, 0, stream>>>(ei, ea, bhist, bb, tmp);
  bucket_sort_kernel<<<NB, 256, 0, stream>>>(bb, tmp, csr, row_off, degw);

  int agg_blocks = (N_NODES + 15) / 16;
  int mv_blocks = (N_NODES + 127) / 128;  // 128 nodes/block -> 782 blocks
  for (int l = 0; l < NLAYER; ++l) {
    matvec3_kernel<<<mv_blocks, 256, 0, stream>>>(
        h, cw1 + l * 4096, cb1 + l * 64, cw2 + l * 4096, cw3 + l * 4096,
        cb3 + l * 64, degw, a_bf, cc_buf);
    agg_kernel<<<agg_blocks, 256, 0, stream>>>(
        a_bf, (const float4*)cc_buf, row_off, csr, (float4*)h);
  }

  head_kernel<<<(N_GRAPHS * 64 + 255) / 256, 256, 0, stream>>>(
      h, batch, l1w, l1b, l2w, l2b, out);
}

// Round 11
// 625.427 us; speedup vs baseline: 2.7767x; 1.1374x over previous
//
#include <hip/hip_runtime.h>

#define N_NODES 100000
#define N_EDGES 3200000
#define N_GRAPHS 1000
#define NLAYER 4
#define NB 391           // coarse buckets: dst>>8, 391*256 = 100096 >= N_NODES
#define G1 782           // edge-pass blocks: 782*4096 >= N_EDGES
#define EPB 4096         // edges per block in edge passes
#define PCAP 16384       // bucket_sort perm capacity (mean bucket 8184, sd ~90)

typedef __attribute__((ext_vector_type(8))) short bf16x8;
typedef __attribute__((ext_vector_type(4))) float f32x4;

// round-to-nearest-even f32 -> bf16 (finite inputs)
static __device__ __forceinline__ unsigned f2bf(float f) {
  unsigned u = __float_as_uint(f);
  return (u + 0x7fffu + ((u >> 16) & 1u)) >> 16;
}

// ---------------------------------------------------------------------------
// h[v][c] = sum_k x[v][k]*emb_w[k][c] + emb_b[c]; also emit bf16 copy
__global__ __launch_bounds__(256) void embed_kernel(
    const float* __restrict__ x, const float* __restrict__ emb_w,
    const float* __restrict__ emb_b, float* __restrict__ h,
    unsigned short* __restrict__ h_bf)
{
  int t = blockIdx.x * 256 + threadIdx.x;
  if (t >= N_NODES * 64) return;
  int c = t & 63, v = t >> 6;
  float4 xv = ((const float4*)x)[v];
  float acc = emb_b[c];
  acc = fmaf(xv.x, emb_w[0 * 64 + c], acc);
  acc = fmaf(xv.y, emb_w[1 * 64 + c], acc);
  acc = fmaf(xv.z, emb_w[2 * 64 + c], acc);
  acc = fmaf(xv.w, emb_w[3 * 64 + c], acc);
  h[t] = acc;
  h_bf[t] = (unsigned short)f2bf(acc);
}

// ---------------------------------------------------------------------------
// A: per-block LDS histogram of coarse bucket (dst>>8). No device atomics.
__global__ __launch_bounds__(256) void bhist_kernel(
    const int* __restrict__ ei, int* __restrict__ bhist)
{
  __shared__ unsigned hist[NB];
  for (int i = threadIdx.x; i < NB; i += 256) hist[i] = 0;
  __syncthreads();
  int base = blockIdx.x * EPB;
#pragma unroll
  for (int i = 0; i < 16; ++i) {
    int e = base + i * 256 + threadIdx.x;
    if (e < N_EDGES) atomicAdd(&hist[((unsigned)ei[N_EDGES + e]) >> 8], 1u);
  }
  __syncthreads();
  for (int i = threadIdx.x; i < NB; i += 256)
    bhist[blockIdx.x * NB + i] = (int)hist[i];
}

// B1: per-bucket column exclusive scan over the G1 block rows (in place);
// column total -> tots[b]
__global__ __launch_bounds__(256) void colscan_kernel(
    int* __restrict__ bhist, int* __restrict__ tots)
{
  int b = blockIdx.x;  // bucket
  __shared__ int s[256];
  __shared__ int carry;
  if (threadIdx.x == 0) carry = 0;
  __syncthreads();
  for (int c0 = 0; c0 < G1; c0 += 256) {
    int g = c0 + threadIdx.x;
    int v = (g < G1) ? bhist[g * NB + b] : 0;
    s[threadIdx.x] = v;
    __syncthreads();
    for (int off = 1; off < 256; off <<= 1) {
      int y = (threadIdx.x >= off) ? s[threadIdx.x - off] : 0;
      __syncthreads();
      s[threadIdx.x] += y;
      __syncthreads();
    }
    if (g < G1) bhist[g * NB + b] = carry + s[threadIdx.x] - v;  // exclusive
    __syncthreads();
    if (threadIdx.x == 0) carry += s[255];
    __syncthreads();
  }
  if (threadIdx.x == 0) tots[b] = carry;
}

// B2: exclusive scan of bucket totals -> bucket base offsets bb[0..NB]
__global__ __launch_bounds__(512) void bucketscan_kernel(
    const int* __restrict__ tots, int* __restrict__ bb)
{
  __shared__ int s[512];
  int x = ((int)threadIdx.x < NB) ? tots[threadIdx.x] : 0;
  s[threadIdx.x] = x;
  __syncthreads();
  for (int off = 1; off < 512; off <<= 1) {
    int y = (threadIdx.x >= off) ? s[threadIdx.x - off] : 0;
    __syncthreads();
    s[threadIdx.x] += y;
    __syncthreads();
  }
  if ((int)threadIdx.x < NB) bb[threadIdx.x] = s[threadIdx.x] - x;
  if (threadIdx.x == 0) bb[NB] = N_EDGES;
}

// C: scatter edges into coarse buckets, LDS-staged for coalesced writes.
// record: x = src | ((dst&255)<<17)   (src < 2^17), y = ew bits (exact f32)
__global__ __launch_bounds__(256) void bscatter_kernel(
    const int* __restrict__ ei, const float* __restrict__ ea,
    const int* __restrict__ bhist, const int* __restrict__ bb,
    int2* __restrict__ tmp)
{
  __shared__ unsigned hist[NB];
  __shared__ int lbase[NB];
  __shared__ unsigned cur[NB];
  __shared__ int2 stage[EPB];          // 32 KB
  __shared__ unsigned short bid[EPB];  // 8 KB
  __shared__ int carry;
  __shared__ int sbuf[256];
  int tid = threadIdx.x;
  int base = blockIdx.x * EPB;

  for (int i = tid; i < NB; i += 256) hist[i] = 0;
  if (tid == 0) carry = 0;
  __syncthreads();

#pragma unroll
  for (int i = 0; i < 16; ++i) {
    int e = base + i * 256 + tid;
    if (e < N_EDGES) atomicAdd(&hist[((unsigned)ei[N_EDGES + e]) >> 8], 1u);
  }
  __syncthreads();

  for (int c0 = 0; c0 < NB; c0 += 256) {
    int g = c0 + tid;
    int v = (g < NB) ? (int)hist[g] : 0;
    sbuf[tid] = v;
    __syncthreads();
    for (int off = 1; off < 256; off <<= 1) {
      int y = (tid >= off) ? sbuf[tid - off] : 0;
      __syncthreads();
      sbuf[tid] += y;
      __syncthreads();
    }
    if (g < NB) {
      int ex = carry + sbuf[tid] - v;
      lbase[g] = ex;
      cur[g] = (unsigned)ex;
    }
    __syncthreads();
    if (tid == 0) carry += sbuf[255];
    __syncthreads();
  }

#pragma unroll
  for (int i = 0; i < 16; ++i) {
    int e = base + i * 256 + tid;
    if (e < N_EDGES) {
      int d = ei[N_EDGES + e];
      unsigned bkt = ((unsigned)d) >> 8;
      unsigned lp = atomicAdd(&cur[bkt], 1u);
      stage[lp] = make_int2(ei[e] | ((d & 255) << 17), __float_as_int(ea[e]));
      bid[lp] = (unsigned short)bkt;
    }
  }
  __syncthreads();

  int nE = min(EPB, N_EDGES - base);
  for (int i = tid; i < nE; i += 256) {
    int bkt = (int)bid[i];
    int gpos = bb[bkt] + bhist[blockIdx.x * NB + bkt] + (i - lbase[bkt]);
    tmp[gpos] = stage[i];
  }
}

// D: one block per bucket: 256-bin LDS counting sort (u16 permutation) ->
// contiguous streaming csr write; emits row_off and degw.
__global__ __launch_bounds__(256) void bucket_sort_kernel(
    const int* __restrict__ bb, const int2* __restrict__ tmp,
    int2* __restrict__ csr, int* __restrict__ row_off, float* __restrict__ degw)
{
  int j = blockIdx.x;
  int b0 = bb[j], b1 = bb[j + 1];
  int nE = b1 - b0;
  __shared__ unsigned hist[256];
  __shared__ float dws[256];
  __shared__ int scanbuf[256];
  __shared__ unsigned cur[256];
  __shared__ unsigned short perm[PCAP];  // 32 KB
  int t = threadIdx.x;
  hist[t] = 0;
  dws[t] = 0.f;
  __syncthreads();
  for (int i = t; i < nE; i += 256) {
    int2 r = tmp[b0 + i];
    int bin = ((unsigned)r.x) >> 17;
    atomicAdd(&hist[bin], 1u);
    atomicAdd(&dws[bin], __int_as_float(r.y));
  }
  __syncthreads();
  int v = (int)hist[t];
  scanbuf[t] = v;
  __syncthreads();
  for (int off = 1; off < 256; off <<= 1) {
    int y = (t >= off) ? scanbuf[t - off] : 0;
    __syncthreads();
    scanbuf[t] += y;
    __syncthreads();
  }
  int myexcl = scanbuf[t] - v;
  cur[t] = (unsigned)myexcl;
  int vnode = (j << 8) + t;
  if (vnode < N_NODES) {
    row_off[vnode] = b0 + myexcl;
    degw[vnode] = dws[t];
  }
  if (j == NB - 1 && t == 0) row_off[N_NODES] = N_EDGES;
  __syncthreads();

  if (nE <= PCAP) {
    for (int i = t; i < nE; i += 256) {
      int2 r = tmp[b0 + i];
      int bin = ((unsigned)r.x) >> 17;
      unsigned p = atomicAdd(&cur[bin], 1u);
      perm[p] = (unsigned short)i;
    }
    __syncthreads();
    for (int q = t; q < nE; q += 256) {
      int2 r = tmp[b0 + (int)perm[q]];
      csr[b0 + q] = make_int2(r.x & 0x1FFFF, r.y);
    }
  } else {
    for (int i = t; i < nE; i += 256) {
      int2 r = tmp[b0 + i];
      int bin = ((unsigned)r.x) >> 17;
      unsigned p = atomicAdd(&cur[bin], 1u);
      csr[b0 + (int)p] = make_int2(r.x & 0x1FFFF, r.y);
    }
  }
}

// ---------------------------------------------------------------------------
// MFMA matvec: per wave 16 nodes, all 64 channels.
//   a_out  = bf16(h@W1 + b1)
//   cc_out = b3 + h@W3 - deg_w*(h@W2)
// A-frags: direct 16B loads from h_bf (A[m=lane&15][k=quad*8+j], verified
// layout). B-frags pre-swizzled into 24 KB LDS (lane-contiguous, conflict-
// free b128). C/D: col=lane&15, row=quad*4+reg -> dw applied per reg.
__global__ __launch_bounds__(256) void matvec3_mfma_kernel(
    const unsigned short* __restrict__ h_bf,
    const float* __restrict__ w1, const float* __restrict__ b1,
    const float* __restrict__ w2,
    const float* __restrict__ w3, const float* __restrict__ b3,
    const float* __restrict__ degw,
    unsigned short* __restrict__ a_bf, float* __restrict__ cc_out)
{
  __shared__ unsigned wfrag[6144];  // [m][c][t][lane][4 uints] = 24 KB
  int tid = threadIdx.x;
  {
    const float* wm0 = w2;
    const float* wm1 = w3;
    const float* wm2 = w1;
    for (int u = tid; u < 6144; u += 256) {
      int j2 = u & 3;
      int lane = (u >> 2) & 63;
      int t = (u >> 8) & 3;
      int c = (u >> 10) & 1;
      int m = u >> 11;
      int k = c * 32 + (lane >> 4) * 8 + j2 * 2;
      int n = t * 16 + (lane & 15);
      const float* W = (m == 0) ? wm0 : (m == 1) ? wm1 : wm2;
      unsigned lo = f2bf(W[k * 64 + n]);
      unsigned hi = f2bf(W[(k + 1) * 64 + n]);
      wfrag[u] = lo | (hi << 16);
    }
  }
  __syncthreads();

  int wave = tid >> 6;
  int lane = tid & 63;
  int quad = lane >> 4;
  int col = lane & 15;
  int nb = blockIdx.x * 64 + wave * 16;  // node base of this wave's 16 rows

  int arow = nb + col;
  if (arow >= N_NODES) arow = N_NODES - 1;
  const bf16x8* ap = (const bf16x8*)(h_bf + (size_t)arow * 64 + quad * 8);
  bf16x8 af0 = ap[0];  // k-chunk 0: k = quad*8 + j
  bf16x8 af1 = ap[4];  // k-chunk 1: k = 32 + quad*8 + j

  float dwr[4];
#pragma unroll
  for (int r = 0; r < 4; ++r) {
    int row = nb + quad * 4 + r;
    dwr[r] = degw[row < N_NODES ? row : 0];
  }

#pragma unroll
  for (int t = 0; t < 4; ++t) {
    const bf16x8* b20 = (const bf16x8*)&wfrag[((0 * 4 + t) << 8) + lane * 4];
    const bf16x8* b21 = (const bf16x8*)&wfrag[((1 * 4 + t) << 8) + lane * 4];
    const bf16x8* b30 = (const bf16x8*)&wfrag[((2 * 4 + t) << 8) + lane * 4];
    const bf16x8* b31 = (const bf16x8*)&wfrag[((3 * 4 + t) << 8) + lane * 4];
    const bf16x8* b10 = (const bf16x8*)&wfrag[((4 * 4 + t) << 8) + lane * 4];
    const bf16x8* b11 = (const bf16x8*)&wfrag[((5 * 4 + t) << 8) + lane * 4];

    f32x4 z = {0.f, 0.f, 0.f, 0.f};
    f32x4 acc2 = __builtin_amdgcn_mfma_f32_16x16x32_bf16(af0, *b20, z, 0, 0, 0);
    acc2 = __builtin_amdgcn_mfma_f32_16x16x32_bf16(af1, *b21, acc2, 0, 0, 0);
    f32x4 cc;
#pragma unroll
    for (int r = 0; r < 4; ++r) cc[r] = -dwr[r] * acc2[r];
    cc = __builtin_amdgcn_mfma_f32_16x16x32_bf16(af0, *b30, cc, 0, 0, 0);
    cc = __builtin_amdgcn_mfma_f32_16x16x32_bf16(af1, *b31, cc, 0, 0, 0);
    float bb3 = b3[t * 16 + col];
#pragma unroll
    for (int r = 0; r < 4; ++r) {
      int row = nb + quad * 4 + r;
      if (row < N_NODES) cc_out[(size_t)row * 64 + t * 16 + col] = cc[r] + bb3;
    }

    float bb1 = b1[t * 16 + col];
    f32x4 a1 = {bb1, bb1, bb1, bb1};
    a1 = __builtin_amdgcn_mfma_f32_16x16x32_bf16(af0, *b10, a1, 0, 0, 0);
    a1 = __builtin_amdgcn_mfma_f32_16x16x32_bf16(af1, *b11, a1, 0, 0, 0);
#pragma unroll
    for (int r = 0; r < 4; ++r) {
      int row = nb + quad * 4 + r;
      if (row < N_NODES)
        a_bf[(size_t)row * 64 + t * 16 + col] = (unsigned short)f2bf(a1[r]);
    }
  }
}

// ---------------------------------------------------------------------------
// h_new[v] = relu(cc[v] + sum_{e in CSR(v)} ew_e * a[src_e])
// 4 nodes/wave, 16 lanes per node; a-rows bf16 (128 B). Writes fp32 h and
// bf16 h_bf (next layer's MFMA A operand).
__global__ __launch_bounds__(256) void agg_kernel(
    const uint2* __restrict__ a2, const float4* __restrict__ cc4,
    const int* __restrict__ row_off, const int2* __restrict__ csr,
    float4* __restrict__ h4, unsigned short* __restrict__ h_bf)
{
  int wave = (blockIdx.x * 256 + threadIdx.x) >> 6;
  int lane = threadIdx.x & 63;
  int sg = lane >> 4;
  int li = lane & 15;
  int v = wave * 4 + sg;
  bool valid = v < N_NODES;
  int vc = valid ? v : N_NODES - 1;
  int base = row_off[vc];
  int ecnt = valid ? (row_off[vc + 1] - base) : 0;
  int emax = ecnt;
  emax = max(emax, __shfl_xor(emax, 16));
  emax = max(emax, __shfl_xor(emax, 32));

  float4 acc = valid ? cc4[(size_t)vc * 16 + li] : make_float4(0.f, 0.f, 0.f, 0.f);

  int full = emax & ~15;
  int c0 = 0;
  for (; c0 < full; c0 += 16) {
    int idx = c0 + li;
    int2 er = (idx < ecnt) ? csr[base + idx] : make_int2(0, 0);
#pragma unroll
    for (int j = 0; j < 16; ++j) {
      int sl = sg * 16 + j;
      int s = __shfl(er.x, sl);
      float w = __int_as_float(__shfl(er.y, sl));
      uint2 u = a2[(size_t)s * 16 + li];
      acc.x = fmaf(w, __uint_as_float(u.x << 16), acc.x);
      acc.y = fmaf(w, __uint_as_float(u.x & 0xffff0000u), acc.y);
      acc.z = fmaf(w, __uint_as_float(u.y << 16), acc.z);
      acc.w = fmaf(w, __uint_as_float(u.y & 0xffff0000u), acc.w);
    }
  }
  int rem = emax - full;
  if (rem > 0) {
    int idx = c0 + li;
    int2 er = (idx < ecnt) ? csr[base + idx] : make_int2(0, 0);
    for (int j = 0; j < rem; ++j) {
      int sl = sg * 16 + j;
      int s = __shfl(er.x, sl);
      float w = __int_as_float(__shfl(er.y, sl));
      uint2 u = a2[(size_t)s * 16 + li];
      acc.x = fmaf(w, __uint_as_float(u.x << 16), acc.x);
      acc.y = fmaf(w, __uint_as_float(u.x & 0xffff0000u), acc.y);
      acc.z = fmaf(w, __uint_as_float(u.y << 16), acc.z);
      acc.w = fmaf(w, __uint_as_float(u.y & 0xffff0000u), acc.w);
    }
  }
  if (valid) {
    acc.x = fmaxf(acc.x, 0.f);
    acc.y = fmaxf(acc.y, 0.f);
    acc.z = fmaxf(acc.z, 0.f);
    acc.w = fmaxf(acc.w, 0.f);
    h4[(size_t)v * 16 + li] = acc;
    uint2 p;
    p.x = f2bf(acc.x) | (f2bf(acc.y) << 16);
    p.y = f2bf(acc.z) | (f2bf(acc.w) << 16);
    ((uint2*)h_bf)[(size_t)v * 16 + li] = p;
  }
}

// ---------------------------------------------------------------------------
// fused mean-pool (sorted batch, binary search) + lin1+relu + lin2, wave/graph
__global__ __launch_bounds__(256) void head_kernel(
    const float* __restrict__ h, const int* __restrict__ batch,
    const float* __restrict__ l1w, const float* __restrict__ l1b,
    const float* __restrict__ l2w, const float* __restrict__ l2b,
    float* __restrict__ out)
{
  int g = (blockIdx.x * 256 + threadIdx.x) >> 6;
  int lane = threadIdx.x & 63;
  if (g >= N_GRAPHS) return;
  int lo = 0, hi = N_NODES;
  while (lo < hi) { int mid = (lo + hi) >> 1; if (batch[mid] < g) lo = mid + 1; else hi = mid; }
  int start = lo;
  hi = N_NODES;
  while (lo < hi) { int mid = (lo + hi) >> 1; if (batch[mid] < g + 1) lo = mid + 1; else hi = mid; }
  int end = lo;

  float sum = 0.f;
  for (int v = start; v < end; ++v) sum += h[(size_t)v * 64 + lane];
  float cntf = (float)(end - start);
  float gx = sum / fmaxf(cntf, 1.f);

  float acc = l1b[lane];
  for (int k = 0; k < 64; ++k) {
    float gxk = __shfl(gx, k);
    acc = fmaf(gxk, l1w[k * 64 + lane], acc);
  }
  float t = fmaxf(acc, 0.f);
  float p0 = t * l2w[lane * 3 + 0];
  float p1 = t * l2w[lane * 3 + 1];
  float p2 = t * l2w[lane * 3 + 2];
  for (int off = 32; off > 0; off >>= 1) {
    p0 += __shfl_down(p0, off);
    p1 += __shfl_down(p1, off);
    p2 += __shfl_down(p2, off);
  }
  if (lane == 0) {
    out[g * 3 + 0] = p0 + l2b[0];
    out[g * 3 + 1] = p1 + l2b[1];
    out[g * 3 + 2] = p2 + l2b[2];
  }
}

// ---------------------------------------------------------------------------
extern "C" void kernel_launch(void* const* d_in, const int* in_sizes, int n_in,
                              void* d_out, int out_size, void* d_ws, size_t ws_size,
                              hipStream_t stream)
{
  (void)in_sizes; (void)n_in; (void)out_size; (void)ws_size;
  const float* x     = (const float*)d_in[0];
  const int*   ei    = (const int*)d_in[1];
  const float* ea    = (const float*)d_in[2];
  const int*   batch = (const int*)d_in[3];
  const float* emb_w = (const float*)d_in[4];
  const float* emb_b = (const float*)d_in[5];
  const float* cw1   = (const float*)d_in[6];
  const float* cb1   = (const float*)d_in[7];
  const float* cw2   = (const float*)d_in[8];
  const float* cw3   = (const float*)d_in[9];
  const float* cb3   = (const float*)d_in[10];
  const float* l1w   = (const float*)d_in[11];
  const float* l1b   = (const float*)d_in[12];
  const float* l2w   = (const float*)d_in[13];
  const float* l2b   = (const float*)d_in[14];
  float* out = (float*)d_out;

  char* wsb = (char*)d_ws;
  size_t off = 0;
  auto alloc = [&](size_t bytes) {
    char* p = wsb + off;
    off = (off + bytes + 255) & ~(size_t)255;
    return p;
  };
  float* h       = (float*)alloc(sizeof(float) * (size_t)N_NODES * 64);
  unsigned short* h_bf = (unsigned short*)alloc(sizeof(short) * (size_t)N_NODES * 64);
  unsigned short* a_bf = (unsigned short*)alloc(sizeof(short) * (size_t)N_NODES * 64);
  float* cc_buf  = (float*)alloc(sizeof(float) * (size_t)N_NODES * 64);
  int2*  csr     = (int2*)alloc(sizeof(int2) * (size_t)N_EDGES);
  int*   row_off = (int*)alloc(sizeof(int) * (N_NODES + 1));
  float* degw    = (float*)alloc(sizeof(float) * N_NODES);
  int*   bhist   = (int*)alloc(sizeof(int) * (size_t)G1 * NB);
  int*   tots    = (int*)alloc(sizeof(int) * NB);
  int*   bb      = (int*)alloc(sizeof(int) * (NB + 1));
  // tmp bucket records alias cc_buf: tmp is dead before matvec first writes cc.
  int2* tmp = (int2*)cc_buf;

  embed_kernel<<<(N_NODES * 64 + 255) / 256, 256, 0, stream>>>(x, emb_w, emb_b, h, h_bf);
  bhist_kernel<<<G1, 256, 0, stream>>>(ei, bhist);
  colscan_kernel<<<NB, 256, 0, stream>>>(bhist, tots);
  bucketscan_kernel<<<1, 512, 0, stream>>>(tots, bb);
  bscatter_kernel<<<G1, 256, 0, stream>>>(ei, ea, bhist, bb, tmp);
  bucket_sort_kernel<<<NB, 256, 0, stream>>>(bb, tmp, csr, row_off, degw);

  int agg_blocks = (N_NODES + 15) / 16;
  int mv_blocks = (N_NODES + 63) / 64;  // 64 nodes/block (4 waves x 16)
  for (int l = 0; l < NLAYER; ++l) {
    matvec3_mfma_kernel<<<mv_blocks, 256, 0, stream>>>(
        h_bf, cw1 + l * 4096, cb1 + l * 64, cw2 + l * 4096, cw3 + l * 4096,
        cb3 + l * 64, degw, a_bf, cc_buf);
    agg_kernel<<<agg_blocks, 256, 0, stream>>>(
        (const uint2*)a_bf, (const float4*)cc_buf, row_off, csr, (float4*)h, h_bf);
  }

  head_kernel<<<(N_GRAPHS * 64 + 255) / 256, 256, 0, stream>>>(
      h, batch, l1w, l1b, l2w, l2b, out);
}

// Round 13
// 537.922 us; speedup vs baseline: 3.2283x; 1.1627x over previous
//
#include <hip/hip_runtime.h>

#define N_NODES 100000
#define N_EDGES 3200000
#define N_GRAPHS 1000
#define NLAYER 4
#define NB 391           // coarse buckets: dst>>8, 391*256 = 100096 >= N_NODES
#define G1 782           // edge-pass blocks: 782*4096 >= N_EDGES
#define EPB 4096         // edges per block in edge passes
#define PCAP 16384       // bucket_sort perm capacity (mean bucket 8184, sd ~90)

typedef __attribute__((ext_vector_type(8))) short bf16x8;
typedef __attribute__((ext_vector_type(4))) float f32x4;

// round-to-nearest-even f32 -> bf16 (finite inputs)
static __device__ __forceinline__ unsigned f2bf(float f) {
  unsigned u = __float_as_uint(f);
  return (u + 0x7fffu + ((u >> 16) & 1u)) >> 16;
}
static __device__ __forceinline__ float bf2f_lo(unsigned u) {
  return __uint_as_float(u << 16);
}
static __device__ __forceinline__ float bf2f_hi(unsigned u) {
  return __uint_as_float(u & 0xffff0000u);
}

// ---------------------------------------------------------------------------
// h_bf[v][c] = bf16(sum_k x[v][k]*emb_w[k][c] + emb_b[c])  (no fp32 h output:
// h fp32 is only needed after the LAST layer's agg)
__global__ __launch_bounds__(256) void embed_kernel(
    const float* __restrict__ x, const float* __restrict__ emb_w,
    const float* __restrict__ emb_b, unsigned short* __restrict__ h_bf)
{
  int t = blockIdx.x * 256 + threadIdx.x;
  if (t >= N_NODES * 64) return;
  int c = t & 63, v = t >> 6;
  float4 xv = ((const float4*)x)[v];
  float acc = emb_b[c];
  acc = fmaf(xv.x, emb_w[0 * 64 + c], acc);
  acc = fmaf(xv.y, emb_w[1 * 64 + c], acc);
  acc = fmaf(xv.z, emb_w[2 * 64 + c], acc);
  acc = fmaf(xv.w, emb_w[3 * 64 + c], acc);
  h_bf[t] = (unsigned short)f2bf(acc);
}

// ---------------------------------------------------------------------------
// A: per-block LDS histogram of coarse bucket (dst>>8). No device atomics.
__global__ __launch_bounds__(256) void bhist_kernel(
    const int* __restrict__ ei, int* __restrict__ bhist)
{
  __shared__ unsigned hist[NB];
  for (int i = threadIdx.x; i < NB; i += 256) hist[i] = 0;
  __syncthreads();
  int base = blockIdx.x * EPB;
#pragma unroll
  for (int i = 0; i < 16; ++i) {
    int e = base + i * 256 + threadIdx.x;
    if (e < N_EDGES) atomicAdd(&hist[((unsigned)ei[N_EDGES + e]) >> 8], 1u);
  }
  __syncthreads();
  for (int i = threadIdx.x; i < NB; i += 256)
    bhist[blockIdx.x * NB + i] = (int)hist[i];
}

// B1: per-bucket column exclusive scan over the G1 block rows (in place);
// column total -> tots[b]
__global__ __launch_bounds__(256) void colscan_kernel(
    int* __restrict__ bhist, int* __restrict__ tots)
{
  int b = blockIdx.x;  // bucket
  __shared__ int s[256];
  __shared__ int carry;
  if (threadIdx.x == 0) carry = 0;
  __syncthreads();
  for (int c0 = 0; c0 < G1; c0 += 256) {
    int g = c0 + threadIdx.x;
    int v = (g < G1) ? bhist[g * NB + b] : 0;
    s[threadIdx.x] = v;
    __syncthreads();
    for (int off = 1; off < 256; off <<= 1) {
      int y = (threadIdx.x >= off) ? s[threadIdx.x - off] : 0;
      __syncthreads();
      s[threadIdx.x] += y;
      __syncthreads();
    }
    if (g < G1) bhist[g * NB + b] = carry + s[threadIdx.x] - v;  // exclusive
    __syncthreads();
    if (threadIdx.x == 0) carry += s[255];
    __syncthreads();
  }
  if (threadIdx.x == 0) tots[b] = carry;
}

// B2: exclusive scan of bucket totals -> bucket base offsets bb[0..NB]
__global__ __launch_bounds__(512) void bucketscan_kernel(
    const int* __restrict__ tots, int* __restrict__ bb)
{
  __shared__ int s[512];
  int x = ((int)threadIdx.x < NB) ? tots[threadIdx.x] : 0;
  s[threadIdx.x] = x;
  __syncthreads();
  for (int off = 1; off < 512; off <<= 1) {
    int y = (threadIdx.x >= off) ? s[threadIdx.x - off] : 0;
    __syncthreads();
    s[threadIdx.x] += y;
    __syncthreads();
  }
  if ((int)threadIdx.x < NB) bb[threadIdx.x] = s[threadIdx.x] - x;
  if (threadIdx.x == 0) bb[NB] = N_EDGES;
}

// C: scatter edges into coarse buckets, LDS-staged for coalesced writes.
// tmp record: x = src | ((dst&255)<<17), y = ew bits (exact f32)
__global__ __launch_bounds__(256) void bscatter_kernel(
    const int* __restrict__ ei, const float* __restrict__ ea,
    const int* __restrict__ bhist, const int* __restrict__ bb,
    int2* __restrict__ tmp)
{
  __shared__ unsigned hist[NB];
  __shared__ int lbase[NB];
  __shared__ unsigned cur[NB];
  __shared__ int2 stage[EPB];          // 32 KB
  __shared__ unsigned short bid[EPB];  // 8 KB
  __shared__ int carry;
  __shared__ int sbuf[256];
  int tid = threadIdx.x;
  int base = blockIdx.x * EPB;

  for (int i = tid; i < NB; i += 256) hist[i] = 0;
  if (tid == 0) carry = 0;
  __syncthreads();

#pragma unroll
  for (int i = 0; i < 16; ++i) {
    int e = base + i * 256 + tid;
    if (e < N_EDGES) atomicAdd(&hist[((unsigned)ei[N_EDGES + e]) >> 8], 1u);
  }
  __syncthreads();

  for (int c0 = 0; c0 < NB; c0 += 256) {
    int g = c0 + tid;
    int v = (g < NB) ? (int)hist[g] : 0;
    sbuf[tid] = v;
    __syncthreads();
    for (int off = 1; off < 256; off <<= 1) {
      int y = (tid >= off) ? sbuf[tid - off] : 0;
      __syncthreads();
      sbuf[tid] += y;
      __syncthreads();
    }
    if (g < NB) {
      int ex = carry + sbuf[tid] - v;
      lbase[g] = ex;
      cur[g] = (unsigned)ex;
    }
    __syncthreads();
    if (tid == 0) carry += sbuf[255];
    __syncthreads();
  }

#pragma unroll
  for (int i = 0; i < 16; ++i) {
    int e = base + i * 256 + tid;
    if (e < N_EDGES) {
      int d = ei[N_EDGES + e];
      unsigned bkt = ((unsigned)d) >> 8;
      unsigned lp = atomicAdd(&cur[bkt], 1u);
      stage[lp] = make_int2(ei[e] | ((d & 255) << 17), __float_as_int(ea[e]));
      bid[lp] = (unsigned short)bkt;
    }
  }
  __syncthreads();

  int nE = min(EPB, N_EDGES - base);
  for (int i = tid; i < nE; i += 256) {
    int bkt = (int)bid[i];
    int gpos = bb[bkt] + bhist[blockIdx.x * NB + bkt] + (i - lbase[bkt]);
    tmp[gpos] = stage[i];
  }
}

// D: one block per bucket: 256-bin LDS counting sort (u16 permutation) ->
// contiguous streaming csr write (u32/edge: src 17b | ew*2^15 15b);
// emits row_off and exact fp32 degw.
__global__ __launch_bounds__(256) void bucket_sort_kernel(
    const int* __restrict__ bb, const int2* __restrict__ tmp,
    unsigned* __restrict__ csr, int* __restrict__ row_off, float* __restrict__ degw)
{
  int j = blockIdx.x;
  int b0 = bb[j], b1 = bb[j + 1];
  int nE = b1 - b0;
  __shared__ unsigned hist[256];
  __shared__ float dws[256];
  __shared__ int scanbuf[256];
  __shared__ unsigned cur[256];
  __shared__ unsigned short perm[PCAP];  // 32 KB
  int t = threadIdx.x;
  hist[t] = 0;
  dws[t] = 0.f;
  __syncthreads();
  for (int i = t; i < nE; i += 256) {
    int2 r = tmp[b0 + i];
    int bin = ((unsigned)r.x) >> 17;
    atomicAdd(&hist[bin], 1u);
    atomicAdd(&dws[bin], __int_as_float(r.y));
  }
  __syncthreads();
  int v = (int)hist[t];
  scanbuf[t] = v;
  __syncthreads();
  for (int off = 1; off < 256; off <<= 1) {
    int y = (t >= off) ? scanbuf[t - off] : 0;
    __syncthreads();
    scanbuf[t] += y;
    __syncthreads();
  }
  int myexcl = scanbuf[t] - v;
  cur[t] = (unsigned)myexcl;
  int vnode = (j << 8) + t;
  if (vnode < N_NODES) {
    row_off[vnode] = b0 + myexcl;
    degw[vnode] = dws[t];
  }
  if (j == NB - 1 && t == 0) row_off[N_NODES] = N_EDGES;
  __syncthreads();

  if (nE <= PCAP) {
    for (int i = t; i < nE; i += 256) {
      int2 r = tmp[b0 + i];
      int bin = ((unsigned)r.x) >> 17;
      unsigned p = atomicAdd(&cur[bin], 1u);
      perm[p] = (unsigned short)i;
    }
    __syncthreads();
    for (int q = t; q < nE; q += 256) {
      int2 r = tmp[b0 + (int)perm[q]];
      unsigned q15 = (unsigned)(__int_as_float(r.y) * 32768.0f);  // ew in [0,1)
      csr[b0 + q] = ((unsigned)r.x & 0x1FFFFu) | (q15 << 17);
    }
  } else {
    for (int i = t; i < nE; i += 256) {
      int2 r = tmp[b0 + i];
      int bin = ((unsigned)r.x) >> 17;
      unsigned p = atomicAdd(&cur[bin], 1u);
      unsigned q15 = (unsigned)(__int_as_float(r.y) * 32768.0f);
      csr[b0 + (int)p] = ((unsigned)r.x & 0x1FFFFu) | (q15 << 17);
    }
  }
}

// ---------------------------------------------------------------------------
// MFMA matvec: per wave 4 row-tiles of 16 nodes (256 nodes/block, grid 391).
//   a_bf  = bf16(h@W1 + b1)
//   cc_bf = bf16(b3 + h@W3 - deg_w*(h@W2))
// wfrag built with COALESCED weight reads (lanes sweep n for fixed k-pair);
// identical u-layout to the verified round-11 mapping.
__global__ __launch_bounds__(256) void matvec3_mfma_kernel(
    const unsigned short* __restrict__ h_bf,
    const float* __restrict__ w1, const float* __restrict__ b1,
    const float* __restrict__ w2,
    const float* __restrict__ w3, const float* __restrict__ b3,
    const float* __restrict__ degw,
    unsigned short* __restrict__ a_bf, unsigned short* __restrict__ cc_bf)
{
  __shared__ unsigned wfrag[6144];  // [m][c][t][lane][j2] = 24 KB
  int tid = threadIdx.x;
  {
    // 96 (m,k-pair) combos; 4 per 256-thread sweep; lanes sweep n (coalesced)
    int n = tid & 63;
    int gofs = tid >> 6;
    for (int it = 0; it < 24; ++it) {
      int g = it * 4 + gofs;         // 0..95
      int m = g >> 5;                // 0..2 (0=W2, 1=W3, 2=W1)
      int kp = g & 31;               // k-pair index
      int k = kp * 2;                // even k
      const float* W = (m == 0) ? w2 : (m == 1) ? w3 : w1;
      unsigned lo = f2bf(W[k * 64 + n]);
      unsigned hi = f2bf(W[(k + 1) * 64 + n]);
      int c = k >> 5;
      int kk = k & 31;
      int lane = ((kk >> 3) << 4) | (n & 15);
      int j2 = (kk & 7) >> 1;
      int t = n >> 4;
      wfrag[(((m * 2 + c) * 4 + t) << 8) | (lane << 2) | j2] = lo | (hi << 16);
    }
  }
  __syncthreads();

  int wave = tid >> 6;
  int lane = tid & 63;
  int quad = lane >> 4;
  int col = lane & 15;

#pragma unroll
  for (int tt = 0; tt < 4; ++tt) {
    int nb = blockIdx.x * 256 + wave * 64 + tt * 16;  // node base of 16 rows
    int arow = nb + col;
    if (arow >= N_NODES) arow = N_NODES - 1;
    const bf16x8* ap = (const bf16x8*)(h_bf + (size_t)arow * 64 + quad * 8);
    bf16x8 af0 = ap[0];  // k = quad*8 + j
    bf16x8 af1 = ap[4];  // k = 32 + quad*8 + j

    float dwr[4];
#pragma unroll
    for (int r = 0; r < 4; ++r) {
      int row = nb + quad * 4 + r;
      dwr[r] = degw[row < N_NODES ? row : 0];
    }

#pragma unroll
    for (int t = 0; t < 4; ++t) {
      const bf16x8* b20 = (const bf16x8*)&wfrag[((0 * 4 + t) << 8) + lane * 4];
      const bf16x8* b21 = (const bf16x8*)&wfrag[((1 * 4 + t) << 8) + lane * 4];
      const bf16x8* b30 = (const bf16x8*)&wfrag[((2 * 4 + t) << 8) + lane * 4];
      const bf16x8* b31 = (const bf16x8*)&wfrag[((3 * 4 + t) << 8) + lane * 4];
      const bf16x8* b10 = (const bf16x8*)&wfrag[((4 * 4 + t) << 8) + lane * 4];
      const bf16x8* b11 = (const bf16x8*)&wfrag[((5 * 4 + t) << 8) + lane * 4];

      f32x4 z = {0.f, 0.f, 0.f, 0.f};
      f32x4 acc2 = __builtin_amdgcn_mfma_f32_16x16x32_bf16(af0, *b20, z, 0, 0, 0);
      acc2 = __builtin_amdgcn_mfma_f32_16x16x32_bf16(af1, *b21, acc2, 0, 0, 0);
      f32x4 cc;
#pragma unroll
      for (int r = 0; r < 4; ++r) cc[r] = -dwr[r] * acc2[r];
      cc = __builtin_amdgcn_mfma_f32_16x16x32_bf16(af0, *b30, cc, 0, 0, 0);
      cc = __builtin_amdgcn_mfma_f32_16x16x32_bf16(af1, *b31, cc, 0, 0, 0);
      float bb3 = b3[t * 16 + col];
#pragma unroll
      for (int r = 0; r < 4; ++r) {
        int row = nb + quad * 4 + r;
        if (row < N_NODES)
          cc_bf[(size_t)row * 64 + t * 16 + col] = (unsigned short)f2bf(cc[r] + bb3);
      }

      float bb1 = b1[t * 16 + col];
      f32x4 a1 = {bb1, bb1, bb1, bb1};
      a1 = __builtin_amdgcn_mfma_f32_16x16x32_bf16(af0, *b10, a1, 0, 0, 0);
      a1 = __builtin_amdgcn_mfma_f32_16x16x32_bf16(af1, *b11, a1, 0, 0, 0);
#pragma unroll
      for (int r = 0; r < 4; ++r) {
        int row = nb + quad * 4 + r;
        if (row < N_NODES)
          a_bf[(size_t)row * 64 + t * 16 + col] = (unsigned short)f2bf(a1[r]);
      }
    }
  }
}

// ---------------------------------------------------------------------------
// h_new[v] = relu(cc[v] + sum_{e in CSR(v)} ew_e * a[src_e])
// 4 nodes/wave, 16 lanes per node; a/cc bf16; csr u32 (src|q15<<17).
// Writes h_bf always; fp32 h only when write_h != 0 (last layer, for head).
__global__ __launch_bounds__(256) void agg_kernel(
    const uint2* __restrict__ a2, const uint2* __restrict__ cc2,
    const int* __restrict__ row_off, const unsigned* __restrict__ csr,
    float4* __restrict__ h4, unsigned short* __restrict__ h_bf, int write_h)
{
  int wave = (blockIdx.x * 256 + threadIdx.x) >> 6;
  int lane = threadIdx.x & 63;
  int sg = lane >> 4;
  int li = lane & 15;
  int v = wave * 4 + sg;
  bool valid = v < N_NODES;
  int vc = valid ? v : N_NODES - 1;
  int base = row_off[vc];
  int ecnt = valid ? (row_off[vc + 1] - base) : 0;
  int emax = ecnt;
  emax = max(emax, __shfl_xor(emax, 16));
  emax = max(emax, __shfl_xor(emax, 32));

  float4 acc = make_float4(0.f, 0.f, 0.f, 0.f);
  if (valid) {
    uint2 cu = cc2[(size_t)vc * 16 + li];
    acc.x = bf2f_lo(cu.x);
    acc.y = bf2f_hi(cu.x);
    acc.z = bf2f_lo(cu.y);
    acc.w = bf2f_hi(cu.y);
  }

  int full = emax & ~15;
  int c0 = 0;
  for (; c0 < full; c0 += 16) {
    int idx = c0 + li;
    unsigned er = (idx < ecnt) ? csr[base + idx] : 0u;  // pad: src 0, w 0
#pragma unroll
    for (int j = 0; j < 16; ++j) {
      unsigned r = (unsigned)__shfl((int)er, sg * 16 + j);
      int s = (int)(r & 0x1FFFFu);
      float w = (float)(r >> 17) * (1.0f / 32768.0f);
      uint2 u = a2[(size_t)s * 16 + li];
      acc.x = fmaf(w, bf2f_lo(u.x), acc.x);
      acc.y = fmaf(w, bf2f_hi(u.x), acc.y);
      acc.z = fmaf(w, bf2f_lo(u.y), acc.z);
      acc.w = fmaf(w, bf2f_hi(u.y), acc.w);
    }
  }
  int rem = emax - full;
  if (rem > 0) {
    int idx = c0 + li;
    unsigned er = (idx < ecnt) ? csr[base + idx] : 0u;
    for (int j = 0; j < rem; ++j) {
      unsigned r = (unsigned)__shfl((int)er, sg * 16 + j);
      int s = (int)(r & 0x1FFFFu);
      float w = (float)(r >> 17) * (1.0f / 32768.0f);
      uint2 u = a2[(size_t)s * 16 + li];
      acc.x = fmaf(w, bf2f_lo(u.x), acc.x);
      acc.y = fmaf(w, bf2f_hi(u.x), acc.y);
      acc.z = fmaf(w, bf2f_lo(u.y), acc.z);
      acc.w = fmaf(w, bf2f_hi(u.y), acc.w);
    }
  }
  if (valid) {
    acc.x = fmaxf(acc.x, 0.f);
    acc.y = fmaxf(acc.y, 0.f);
    acc.z = fmaxf(acc.z, 0.f);
    acc.w = fmaxf(acc.w, 0.f);
    if (write_h) h4[(size_t)v * 16 + li] = acc;
    uint2 p;
    p.x = f2bf(acc.x) | (f2bf(acc.y) << 16);
    p.y = f2bf(acc.z) | (f2bf(acc.w) << 16);
    ((uint2*)h_bf)[(size_t)v * 16 + li] = p;
  }
}

// ---------------------------------------------------------------------------
// fused mean-pool (sorted batch, binary search) + lin1+relu + lin2, wave/graph
__global__ __launch_bounds__(256) void head_kernel(
    const float* __restrict__ h, const int* __restrict__ batch,
    const float* __restrict__ l1w, const float* __restrict__ l1b,
    const float* __restrict__ l2w, const float* __restrict__ l2b,
    float* __restrict__ out)
{
  int g = (blockIdx.x * 256 + threadIdx.x) >> 6;
  int lane = threadIdx.x & 63;
  if (g >= N_GRAPHS) return;
  int lo = 0, hi = N_NODES;
  while (lo < hi) { int mid = (lo + hi) >> 1; if (batch[mid] < g) lo = mid + 1; else hi = mid; }
  int start = lo;
  hi = N_NODES;
  while (lo < hi) { int mid = (lo + hi) >> 1; if (batch[mid] < g + 1) lo = mid + 1; else hi = mid; }
  int end = lo;

  float sum = 0.f;
  for (int v = start; v < end; ++v) sum += h[(size_t)v * 64 + lane];
  float cntf = (float)(end - start);
  float gx = sum / fmaxf(cntf, 1.f);

  float acc = l1b[lane];
  for (int k = 0; k < 64; ++k) {
    float gxk = __shfl(gx, k);
    acc = fmaf(gxk, l1w[k * 64 + lane], acc);
  }
  float t = fmaxf(acc, 0.f);
  float p0 = t * l2w[lane * 3 + 0];
  float p1 = t * l2w[lane * 3 + 1];
  float p2 = t * l2w[lane * 3 + 2];
  for (int off = 32; off > 0; off >>= 1) {
    p0 += __shfl_down(p0, off);
    p1 += __shfl_down(p1, off);
    p2 += __shfl_down(p2, off);
  }
  if (lane == 0) {
    out[g * 3 + 0] = p0 + l2b[0];
    out[g * 3 + 1] = p1 + l2b[1];
    out[g * 3 + 2] = p2 + l2b[2];
  }
}

// ---------------------------------------------------------------------------
extern "C" void kernel_launch(void* const* d_in, const int* in_sizes, int n_in,
                              void* d_out, int out_size, void* d_ws, size_t ws_size,
                              hipStream_t stream)
{
  (void)in_sizes; (void)n_in; (void)out_size; (void)ws_size;
  const float* x     = (const float*)d_in[0];
  const int*   ei    = (const int*)d_in[1];
  const float* ea    = (const float*)d_in[2];
  const int*   batch = (const int*)d_in[3];
  const float* emb_w = (const float*)d_in[4];
  const float* emb_b = (const float*)d_in[5];
  const float* cw1   = (const float*)d_in[6];
  const float* cb1   = (const float*)d_in[7];
  const float* cw2   = (const float*)d_in[8];
  const float* cw3   = (const float*)d_in[9];
  const float* cb3   = (const float*)d_in[10];
  const float* l1w   = (const float*)d_in[11];
  const float* l1b   = (const float*)d_in[12];
  const float* l2w   = (const float*)d_in[13];
  const float* l2b   = (const float*)d_in[14];
  float* out = (float*)d_out;

  char* wsb = (char*)d_ws;
  size_t off = 0;
  auto alloc = [&](size_t bytes) {
    char* p = wsb + off;
    off = (off + bytes + 255) & ~(size_t)255;
    return p;
  };
  float* h       = (float*)alloc(sizeof(float) * (size_t)N_NODES * 64);    // 25.6 MB
  unsigned short* h_bf = (unsigned short*)alloc(sizeof(short) * (size_t)N_NODES * 64);
  unsigned short* a_bf = (unsigned short*)alloc(sizeof(short) * (size_t)N_NODES * 64);
  unsigned short* cc_bf = (unsigned short*)alloc(sizeof(short) * (size_t)N_NODES * 64);
  unsigned* csr  = (unsigned*)alloc(sizeof(unsigned) * (size_t)N_EDGES);   // 12.8 MB
  int*   row_off = (int*)alloc(sizeof(int) * (N_NODES + 1));
  float* degw    = (float*)alloc(sizeof(float) * N_NODES);
  int*   bhist   = (int*)alloc(sizeof(int) * (size_t)G1 * NB);
  int*   tots    = (int*)alloc(sizeof(int) * NB);
  int*   bb      = (int*)alloc(sizeof(int) * (NB + 1));
  // tmp (25.6 MB int2) aliases h: h fp32 is only written by the LAST agg,
  // long after bucket_sort consumed tmp.
  int2* tmp = (int2*)h;

  embed_kernel<<<(N_NODES * 64 + 255) / 256, 256, 0, stream>>>(x, emb_w, emb_b, h_bf);
  bhist_kernel<<<G1, 256, 0, stream>>>(ei, bhist);
  colscan_kernel<<<NB, 256, 0, stream>>>(bhist, tots);
  bucketscan_kernel<<<1, 512, 0, stream>>>(tots, bb);
  bscatter_kernel<<<G1, 256, 0, stream>>>(ei, ea, bhist, bb, tmp);
  bucket_sort_kernel<<<NB, 256, 0, stream>>>(bb, tmp, csr, row_off, degw);

  int agg_blocks = (N_NODES + 15) / 16;
  int mv_blocks = (N_NODES + 255) / 256;  // 256 nodes/block -> 391 blocks
  for (int l = 0; l < NLAYER; ++l) {
    matvec3_mfma_kernel<<<mv_blocks, 256, 0, stream>>>(
        h_bf, cw1 + l * 4096, cb1 + l * 64, cw2 + l * 4096, cw3 + l * 4096,
        cb3 + l * 64, degw, a_bf, cc_bf);
    agg_kernel<<<agg_blocks, 256, 0, stream>>>(
        (const uint2*)a_bf, (const uint2*)cc_bf, row_off, csr, (float4*)h,
        h_bf, (l == NLAYER - 1) ? 1 : 0);
  }

  head_kernel<<<(N_GRAPHS * 64 + 255) / 256, 256, 0, stream>>>(
      h, batch, l1w, l1b, l2w, l2b, out);
}